// Round 1
// baseline (7244.900 us; speedup 1.0000x reference)
//
#include <hip/hip_runtime.h>
#include <math.h>

#define T_TOKENS 65536
#define D_DIM    512
#define H_DIM    2048
#define O_DIM    512
#define E_NUM    8
#define CAP      8192

// ---- workspace layout (bytes) ----
static constexpr size_t OFF_COUNTS = 0;                                      // 8 ints
static constexpr size_t OFF_SELC   = 32;                                     // 8 ints
static constexpr size_t OFF_PROC   = 64;                                     // T ints
static constexpr size_t CTRL_BYTES = 64 + (size_t)T_TOKENS * 4;              // zeroed every launch
static constexpr size_t OFF_CANDW  = 262656;                                 // E*T floats
static constexpr size_t OFF_CANDS  = OFF_CANDW + (size_t)E_NUM * T_TOKENS * 4;
static constexpr size_t OFF_SELTOK = OFF_CANDS + (size_t)E_NUM * T_TOKENS * 4;
static constexpr size_t OFF_SELW   = OFF_SELTOK + (size_t)E_NUM * CAP * 4;
static constexpr size_t OFF_XN     = OFF_SELW + (size_t)E_NUM * CAP * 4;     // 4981248 (512-aligned)
static constexpr size_t OFF_H      = OFF_XN + (size_t)T_TOKENS * D_DIM * 4;  // +128MB
// total ≈ 206.3 MB

// ---------------- LayerNorm + router (fp64-exact gates) ----------------
__global__ __launch_bounds__(256) void ln_router_kernel(
    const float* __restrict__ x, const float* __restrict__ noise,
    const float* __restrict__ gamma, const float* __restrict__ beta,
    const float* __restrict__ Wg, const float* __restrict__ bg,
    float* __restrict__ xn,
    int* __restrict__ counts, float* __restrict__ cand_w, int* __restrict__ cand_slot)
{
    __shared__ float sWg[E_NUM * D_DIM];
    for (int i = threadIdx.x; i < E_NUM * D_DIM; i += 256) sWg[i] = Wg[i];
    __syncthreads();

    const int wave = threadIdx.x >> 6;
    const int lane = threadIdx.x & 63;
    const int t = blockIdx.x * 4 + wave;

    const float* xr = x + (size_t)t * D_DIM;
    float xv[8];
    #pragma unroll
    for (int i = 0; i < 8; i++) xv[i] = xr[i * 64 + lane];

    double s = 0.0;
    #pragma unroll
    for (int i = 0; i < 8; i++) s += (double)xv[i];
    #pragma unroll
    for (int off = 32; off > 0; off >>= 1) s += __shfl_down(s, off);
    double mu = __shfl(s, 0) / 512.0;

    double v = 0.0;
    #pragma unroll
    for (int i = 0; i < 8; i++) { double d = (double)xv[i] - mu; v += d * d; }
    #pragma unroll
    for (int off = 32; off > 0; off >>= 1) v += __shfl_down(v, off);
    double var = __shfl(v, 0) / 512.0;
    double rstd = 1.0 / sqrt(var + 1e-5);

    float xnf[8];
    #pragma unroll
    for (int i = 0; i < 8; i++) {
        int c = i * 64 + lane;
        double xd = ((double)xv[i] - mu) * rstd * (double)gamma[c] + (double)beta[c];
        xnf[i] = (float)xd;
        xn[(size_t)t * D_DIM + c] = xnf[i];
    }

    // router logits from the fp32-rounded xn (matches reference dataflow)
    double p[E_NUM];
    #pragma unroll
    for (int e = 0; e < E_NUM; e++) p[e] = 0.0;
    #pragma unroll
    for (int i = 0; i < 8; i++) {
        int c = i * 64 + lane;
        double xd = (double)xnf[i];
        #pragma unroll
        for (int e = 0; e < E_NUM; e++)
            p[e] += xd * (double)sWg[e * D_DIM + c];
    }
    #pragma unroll
    for (int off = 32; off > 0; off >>= 1) {
        #pragma unroll
        for (int e = 0; e < E_NUM; e++) p[e] += __shfl_down(p[e], off);
    }

    if (lane == 0) {
        double l[E_NUM];
        double m = -1e300;
        #pragma unroll
        for (int e = 0; e < E_NUM; e++) {
            l[e] = p[e] + (double)bg[e] + 0.125 * (double)noise[(size_t)t * E_NUM + e];
            if (l[e] > m) m = l[e];
        }
        double sum = 0.0, g[E_NUM];
        #pragma unroll
        for (int e = 0; e < E_NUM; e++) { g[e] = exp(l[e] - m); sum += g[e]; }
        double inv = 1.0 / sum;
        #pragma unroll
        for (int e = 0; e < E_NUM; e++) g[e] *= inv;

        double v1 = -1.0; int i1 = 0;
        #pragma unroll
        for (int e = 0; e < E_NUM; e++) if (g[e] > v1) { v1 = g[e]; i1 = e; }
        double v2 = -1.0; int i2 = 0;
        #pragma unroll
        for (int e = 0; e < E_NUM; e++) if (e != i1 && g[e] > v2) { v2 = g[e]; i2 = e; }

        double denom = v1 + v2 + 1e-20;
        float w1 = (float)(v1 / denom);
        float w2 = (float)(v2 / denom);

        int p1 = atomicAdd(&counts[i1], 1);
        cand_w[i1 * T_TOKENS + p1] = w1;
        cand_slot[i1 * T_TOKENS + p1] = 2 * t;
        int p2 = atomicAdd(&counts[i2], 1);
        cand_w[i2 * T_TOKENS + p2] = w2;
        cand_slot[i2 * T_TOKENS + p2] = 2 * t + 1;
    }
}

// ------------- per-expert exact top-capacity (radix select on 64-bit key) -------------
// key = (~bits(w) << 32) | slot  -> ascending key == (descending w, ascending slot),
// exactly jax.lax.top_k tie semantics on the flat slot array.
__global__ __launch_bounds__(256) void select_kernel(
    const int* __restrict__ counts, const float* __restrict__ cand_w,
    const int* __restrict__ cand_slot, int* __restrict__ sel_count,
    int* __restrict__ sel_tok, float* __restrict__ sel_w, int* __restrict__ processed)
{
    const int e = blockIdx.x;
    const int n = counts[e];
    const float* cw = cand_w + (size_t)e * T_TOKENS;
    const int* cs = cand_slot + (size_t)e * T_TOKENS;

    __shared__ unsigned int hist[256];
    __shared__ unsigned long long sh_pfx;
    __shared__ int sh_need;

    unsigned long long theta = ~0ULL;  // n <= CAP: select everything
    if (n > CAP) {
        unsigned long long pfx = 0;
        int need = CAP;
        for (int shift = 56; shift >= 0; shift -= 8) {
            hist[threadIdx.x] = 0;
            __syncthreads();
            for (int i = threadIdx.x; i < n; i += 256) {
                unsigned int wb = __float_as_uint(cw[i]);
                unsigned long long key = (((unsigned long long)(~wb)) << 32) | (unsigned int)cs[i];
                bool match = (shift == 56) || ((key >> (shift + 8)) == pfx);
                if (match) atomicAdd(&hist[(unsigned int)(key >> shift) & 255u], 1u);
            }
            __syncthreads();
            if (threadIdx.x == 0) {
                unsigned int cum = 0;
                int b = 0;
                for (; b < 255; b++) {
                    if (cum + hist[b] >= (unsigned int)need) break;
                    cum += hist[b];
                }
                sh_pfx = (pfx << 8) | (unsigned long long)(unsigned int)b;
                sh_need = need - (int)cum;
            }
            __syncthreads();
            pfx = sh_pfx;
            need = sh_need;
            __syncthreads();
        }
        theta = pfx;  // the CAP-th smallest key; keys are unique
    }
    __syncthreads();

    for (int i = threadIdx.x; i < n; i += 256) {
        unsigned int wb = __float_as_uint(cw[i]);
        unsigned long long key = (((unsigned long long)(~wb)) << 32) | (unsigned int)cs[i];
        if (key <= theta) {
            int ppos = atomicAdd(&sel_count[e], 1);
            sel_tok[e * CAP + ppos] = cs[i] >> 1;
            sel_w[e * CAP + ppos]  = cw[i];
            processed[cs[i] >> 1] = 1;
        }
    }
}

// ---------------- fc1: h = gelu(xn[tok] @ W1[e] + b1[e]) ----------------
__global__ __launch_bounds__(256) void fc1_kernel(
    const float* __restrict__ xn, const int* __restrict__ sel_tok,
    const int* __restrict__ sel_count, const float* __restrict__ W1,
    const float* __restrict__ b1, float* __restrict__ h, int e)
{
    __shared__ float sA[16][64 + 1];
    __shared__ float sB[16][64 + 1];
    const int selc = sel_count[e];
    const int row0 = blockIdx.x * 64;
    const int col0 = blockIdx.y * 64;
    if (row0 >= selc) return;
    const float* W = W1 + (size_t)e * D_DIM * H_DIM;

    const int lr  = threadIdx.x >> 2;          // 0..63 : A row in tile
    const int lk  = (threadIdx.x & 3) * 4;     // 0..12 : A k (float4)
    const int lbk = threadIdx.x >> 4;          // 0..15 : B k row
    const int lbj = (threadIdx.x & 15) * 4;    // 0..60 : B col (float4)
    const int tx = threadIdx.x & 15, ty = threadIdx.x >> 4;

    const int grow = row0 + lr;
    const int tok = (grow < selc) ? sel_tok[e * CAP + grow] : 0;
    const float* arow = xn + (size_t)tok * D_DIM;

    float acc[4][4] = {};
    for (int k0 = 0; k0 < D_DIM; k0 += 16) {
        float4 av = *(const float4*)(arow + k0 + lk);
        float4 bv = *(const float4*)(W + (size_t)(k0 + lbk) * H_DIM + col0 + lbj);
        sA[lk + 0][lr] = av.x; sA[lk + 1][lr] = av.y; sA[lk + 2][lr] = av.z; sA[lk + 3][lr] = av.w;
        sB[lbk][lbj + 0] = bv.x; sB[lbk][lbj + 1] = bv.y; sB[lbk][lbj + 2] = bv.z; sB[lbk][lbj + 3] = bv.w;
        __syncthreads();
        #pragma unroll
        for (int kk = 0; kk < 16; kk++) {
            float a[4], b[4];
            #pragma unroll
            for (int i = 0; i < 4; i++) a[i] = sA[kk][ty * 4 + i];
            #pragma unroll
            for (int j = 0; j < 4; j++) b[j] = sB[kk][tx * 4 + j];
            #pragma unroll
            for (int i = 0; i < 4; i++)
                #pragma unroll
                for (int j = 0; j < 4; j++)
                    acc[i][j] = fmaf(a[i], b[j], acc[i][j]);
        }
        __syncthreads();
    }
    #pragma unroll
    for (int i = 0; i < 4; i++) {
        int r = row0 + ty * 4 + i;
        if (r < selc) {
            #pragma unroll
            for (int j = 0; j < 4; j++) {
                int c = col0 + tx * 4 + j;
                float pre = acc[i][j] + b1[e * H_DIM + c];
                float gel = 0.5f * pre * (1.0f + erff(pre * 0.70710678118654752440f));
                h[(size_t)r * H_DIM + c] = gel;
            }
        }
    }
}

// ---------------- fc2: out[tok] += w * (h @ W2[e] + b2[e]) ----------------
__global__ __launch_bounds__(256) void fc2_kernel(
    const float* __restrict__ h, const int* __restrict__ sel_tok,
    const float* __restrict__ sel_w, const int* __restrict__ sel_count,
    const float* __restrict__ W2, const float* __restrict__ b2,
    float* __restrict__ out, int e)
{
    __shared__ float sA[16][64 + 1];
    __shared__ float sB[16][64 + 1];
    const int selc = sel_count[e];
    const int row0 = blockIdx.x * 64;
    const int col0 = blockIdx.y * 64;
    if (row0 >= selc) return;
    const float* W = W2 + (size_t)e * H_DIM * O_DIM;

    const int lr  = threadIdx.x >> 2;
    const int lk  = (threadIdx.x & 3) * 4;
    const int lbk = threadIdx.x >> 4;
    const int lbj = (threadIdx.x & 15) * 4;
    const int tx = threadIdx.x & 15, ty = threadIdx.x >> 4;

    const float* arow = h + (size_t)(row0 + lr) * H_DIM;

    float acc[4][4] = {};
    for (int k0 = 0; k0 < H_DIM; k0 += 16) {
        float4 av = *(const float4*)(arow + k0 + lk);
        float4 bv = *(const float4*)(W + (size_t)(k0 + lbk) * O_DIM + col0 + lbj);
        sA[lk + 0][lr] = av.x; sA[lk + 1][lr] = av.y; sA[lk + 2][lr] = av.z; sA[lk + 3][lr] = av.w;
        sB[lbk][lbj + 0] = bv.x; sB[lbk][lbj + 1] = bv.y; sB[lbk][lbj + 2] = bv.z; sB[lbk][lbj + 3] = bv.w;
        __syncthreads();
        #pragma unroll
        for (int kk = 0; kk < 16; kk++) {
            float a[4], b[4];
            #pragma unroll
            for (int i = 0; i < 4; i++) a[i] = sA[kk][ty * 4 + i];
            #pragma unroll
            for (int j = 0; j < 4; j++) b[j] = sB[kk][tx * 4 + j];
            #pragma unroll
            for (int i = 0; i < 4; i++)
                #pragma unroll
                for (int j = 0; j < 4; j++)
                    acc[i][j] = fmaf(a[i], b[j], acc[i][j]);
        }
        __syncthreads();
    }
    #pragma unroll
    for (int i = 0; i < 4; i++) {
        int r = row0 + ty * 4 + i;
        if (r < selc) {
            int tok = sel_tok[e * CAP + r];
            float w = sel_w[e * CAP + r];
            #pragma unroll
            for (int j = 0; j < 4; j++) {
                int c = col0 + tx * 4 + j;
                float val = acc[i][j] + b2[e * O_DIM + c];
                out[(size_t)tok * O_DIM + c] += w * val;  // race-free: tok unique within expert
            }
        }
    }
}

// ---------------- passthrough for unprocessed tokens ----------------
__global__ __launch_bounds__(256) void finalize_kernel(
    const float* __restrict__ xn, const int* __restrict__ processed, float* __restrict__ out)
{
    size_t i = (size_t)blockIdx.x * 256 + threadIdx.x;   // float4 index, total T*O/4
    int t = (int)(i >> 7);                               // 128 float4 per row
    if (!processed[t]) {
        ((float4*)out)[i] = ((const float4*)xn)[i];
    }
}

extern "C" void kernel_launch(void* const* d_in, const int* in_sizes, int n_in,
                              void* d_out, int out_size, void* d_ws, size_t ws_size,
                              hipStream_t stream) {
    const float* x     = (const float*)d_in[0];
    const float* noise = (const float*)d_in[1];
    const float* gamma = (const float*)d_in[2];
    const float* beta  = (const float*)d_in[3];
    const float* Wg    = (const float*)d_in[4];
    const float* bg    = (const float*)d_in[5];
    const float* W1    = (const float*)d_in[6];
    const float* b1    = (const float*)d_in[7];
    const float* W2    = (const float*)d_in[8];
    const float* b2    = (const float*)d_in[9];
    float* out = (float*)d_out;

    char* ws = (char*)d_ws;
    int*   counts    = (int*)(ws + OFF_COUNTS);
    int*   sel_count = (int*)(ws + OFF_SELC);
    int*   processed = (int*)(ws + OFF_PROC);
    float* cand_w    = (float*)(ws + OFF_CANDW);
    int*   cand_slot = (int*)(ws + OFF_CANDS);
    int*   sel_tok   = (int*)(ws + OFF_SELTOK);
    float* sel_w     = (float*)(ws + OFF_SELW);
    float* xn        = (float*)(ws + OFF_XN);
    float* h         = (float*)(ws + OFF_H);

    // zero outputs + control state (must be per-launch: harness poisons once, never re-poisons)
    hipMemsetAsync(d_out, 0, (size_t)out_size * sizeof(float), stream);
    hipMemsetAsync(ws, 0, CTRL_BYTES, stream);

    ln_router_kernel<<<T_TOKENS / 4, 256, 0, stream>>>(
        x, noise, gamma, beta, Wg, bg, xn, counts, cand_w, cand_slot);

    select_kernel<<<E_NUM, 256, 0, stream>>>(
        counts, cand_w, cand_slot, sel_count, sel_tok, sel_w, processed);

    for (int e = 0; e < E_NUM; e++) {
        fc1_kernel<<<dim3(CAP / 64, H_DIM / 64), 256, 0, stream>>>(
            xn, sel_tok, sel_count, W1, b1, h, e);
        fc2_kernel<<<dim3(CAP / 64, O_DIM / 64), 256, 0, stream>>>(
            h, sel_tok, sel_w, sel_count, W2, b2, out, e);
    }

    finalize_kernel<<<(T_TOKENS * O_DIM / 4) / 256, 256, 0, stream>>>(xn, processed, out);
}

// Round 2
// 1310.399 us; speedup vs baseline: 5.5288x; 5.5288x over previous
//
#include <hip/hip_runtime.h>
#include <math.h>

typedef __attribute__((ext_vector_type(4))) float f32x4;
typedef __attribute__((ext_vector_type(8))) short short8;
typedef unsigned short u16;

#define T_TOKENS 65536
#define D_DIM    512
#define H_DIM    2048
#define O_DIM    512
#define E_NUM    8
#define CAP      8192

// ---- workspace layout (bytes) ----
static constexpr size_t OFF_COUNTS = 0;          // 8 ints
static constexpr size_t OFF_SELC   = 64;         // 8 ints
static constexpr size_t OFF_PROC   = 128;        // T ints
static constexpr size_t CTRL_BYTES = 128 + (size_t)T_TOKENS * 4;   // 262272, zeroed per launch
static constexpr size_t OFF_CANDW  = 262656;
static constexpr size_t OFF_CANDS  = OFF_CANDW + (size_t)E_NUM * T_TOKENS * 4;   // +2MB
static constexpr size_t OFF_SELTOK = OFF_CANDS + (size_t)E_NUM * T_TOKENS * 4;   // +2MB
static constexpr size_t OFF_SELW   = OFF_SELTOK + (size_t)E_NUM * CAP * 4;       // +256KB
static constexpr size_t OFF_LOG    = OFF_SELW + (size_t)E_NUM * CAP * 4;         // +256KB
static constexpr size_t OFF_XNB    = OFF_LOG + (size_t)T_TOKENS * E_NUM * 8;     // +4MB
static constexpr size_t OFF_H      = OFF_XNB + (size_t)T_TOKENS * D_DIM * 2;     // +64MB
static constexpr size_t OFF_W1T    = OFF_H + (size_t)CAP * H_DIM * 2;            // +32MB
static constexpr size_t OFF_W2T    = OFF_W1T + (size_t)E_NUM * H_DIM * D_DIM * 2;// +16MB
// end = OFF_W2T + 16MB  ~= 137MB total

__device__ __forceinline__ u16 f2b(float f) {            // f32 -> bf16 RNE
    unsigned u = __float_as_uint(f);
    unsigned r = (u + 0x7FFFu + ((u >> 16) & 1u)) >> 16;
    return (u16)r;
}
__device__ __forceinline__ float b2f(u16 b) {
    return __uint_as_float(((unsigned)b) << 16);
}

#define AS1 __attribute__((address_space(1)))
#define AS3 __attribute__((address_space(3)))
__device__ __forceinline__ void gload_lds16(const void* g, void* l) {
    __builtin_amdgcn_global_load_lds((const AS1 void*)g, (AS3 void*)l, 16, 0, 0);
}

// ---------------- LayerNorm + fp64 logits (decision math identical to passing round) ----------------
__global__ __launch_bounds__(256) void ln_kernel(
    const float* __restrict__ x, const float* __restrict__ gamma,
    const float* __restrict__ beta, const float* __restrict__ Wg,
    u16* __restrict__ xnb, double* __restrict__ logits)
{
    __shared__ float sWg[E_NUM * D_DIM];
    for (int i = threadIdx.x; i < E_NUM * D_DIM; i += 256) sWg[i] = Wg[i];
    __syncthreads();

    const int wave = threadIdx.x >> 6, lane = threadIdx.x & 63;
    const int t = blockIdx.x * 4 + wave;
    const float* xr = x + (size_t)t * D_DIM;

    float xv[8];
    #pragma unroll
    for (int i = 0; i < 8; i++) xv[i] = xr[i * 64 + lane];

    double s = 0.0;
    #pragma unroll
    for (int i = 0; i < 8; i++) s += (double)xv[i];
    #pragma unroll
    for (int o = 32; o > 0; o >>= 1) s += __shfl_xor(s, o);
    double mu = s / 512.0;

    double v = 0.0;
    #pragma unroll
    for (int i = 0; i < 8; i++) { double d = (double)xv[i] - mu; v += d * d; }
    #pragma unroll
    for (int o = 32; o > 0; o >>= 1) v += __shfl_xor(v, o);
    double rstd = 1.0 / sqrt(v / 512.0 + 1e-5);

    float xnf[8];
    #pragma unroll
    for (int i = 0; i < 8; i++) {
        int c = i * 64 + lane;
        double xd = ((double)xv[i] - mu) * rstd * (double)gamma[c] + (double)beta[c];
        xnf[i] = (float)xd;
        xnb[(size_t)t * D_DIM + c] = f2b(xnf[i]);
    }

    double p[E_NUM];
    #pragma unroll
    for (int e = 0; e < E_NUM; e++) p[e] = 0.0;
    #pragma unroll
    for (int i = 0; i < 8; i++) {
        int c = i * 64 + lane;
        double xd = (double)xnf[i];
        #pragma unroll
        for (int e = 0; e < E_NUM; e++) p[e] += xd * (double)sWg[e * D_DIM + c];
    }
    #pragma unroll
    for (int o = 32; o > 0; o >>= 1) {
        #pragma unroll
        for (int e = 0; e < E_NUM; e++) p[e] += __shfl_xor(p[e], o);
    }
    if (lane < 8) {
        double vv = p[0];
        #pragma unroll
        for (int e = 1; e < 8; e++) if (lane == e) vv = p[e];
        logits[(size_t)t * 8 + lane] = vv;
    }
}

// ---------------- gate: softmax + top2 + normalize, thread-per-token ----------------
__global__ __launch_bounds__(256) void gate_kernel(
    const double* __restrict__ logits, const float* __restrict__ noise,
    const float* __restrict__ bg,
    int* __restrict__ counts, float* __restrict__ cand_w, int* __restrict__ cand_slot)
{
    __shared__ int lcnt[E_NUM], lbase[E_NUM];
    if (threadIdx.x < E_NUM) lcnt[threadIdx.x] = 0;
    __syncthreads();
    const int t = blockIdx.x * 256 + threadIdx.x;

    double l[E_NUM], m = -1e300;
    #pragma unroll
    for (int e = 0; e < E_NUM; e++) {
        l[e] = logits[(size_t)t * 8 + e] + (double)bg[e] + 0.125 * (double)noise[(size_t)t * 8 + e];
        if (l[e] > m) m = l[e];
    }
    double sum = 0.0, g[E_NUM];
    #pragma unroll
    for (int e = 0; e < E_NUM; e++) { g[e] = exp(l[e] - m); sum += g[e]; }
    double inv = 1.0 / sum;
    #pragma unroll
    for (int e = 0; e < E_NUM; e++) g[e] *= inv;

    double v1 = -1.0; int i1 = 0;
    #pragma unroll
    for (int e = 0; e < E_NUM; e++) if (g[e] > v1) { v1 = g[e]; i1 = e; }
    double v2 = -1.0; int i2 = 0;
    #pragma unroll
    for (int e = 0; e < E_NUM; e++) if (e != i1 && g[e] > v2) { v2 = g[e]; i2 = e; }

    double denom = v1 + v2 + 1e-20;
    float w1 = (float)(v1 / denom);
    float w2 = (float)(v2 / denom);

    int p1 = atomicAdd(&lcnt[i1], 1);
    int p2 = atomicAdd(&lcnt[i2], 1);
    __syncthreads();
    if (threadIdx.x < E_NUM) lbase[threadIdx.x] = atomicAdd(&counts[threadIdx.x], lcnt[threadIdx.x]);
    __syncthreads();
    cand_w[(size_t)i1 * T_TOKENS + lbase[i1] + p1] = w1;
    cand_slot[(size_t)i1 * T_TOKENS + lbase[i1] + p1] = 2 * t;
    cand_w[(size_t)i2 * T_TOKENS + lbase[i2] + p2] = w2;
    cand_slot[(size_t)i2 * T_TOKENS + lbase[i2] + p2] = 2 * t + 1;
}

// ------------- per-expert exact top-capacity (radix select, unchanged from passing round) -------------
__global__ __launch_bounds__(256) void select_kernel(
    const int* __restrict__ counts, const float* __restrict__ cand_w,
    const int* __restrict__ cand_slot, int* __restrict__ sel_count,
    int* __restrict__ sel_tok, float* __restrict__ sel_w, int* __restrict__ processed)
{
    const int e = blockIdx.x;
    const int n = counts[e];
    const float* cw = cand_w + (size_t)e * T_TOKENS;
    const int* cs = cand_slot + (size_t)e * T_TOKENS;

    __shared__ unsigned int hist[256];
    __shared__ unsigned long long sh_pfx;
    __shared__ int sh_need;

    unsigned long long theta = ~0ULL;
    if (n > CAP) {
        unsigned long long pfx = 0;
        int need = CAP;
        for (int shift = 56; shift >= 0; shift -= 8) {
            hist[threadIdx.x] = 0;
            __syncthreads();
            for (int i = threadIdx.x; i < n; i += 256) {
                unsigned int wb = __float_as_uint(cw[i]);
                unsigned long long key = (((unsigned long long)(~wb)) << 32) | (unsigned int)cs[i];
                bool match = (shift == 56) || ((key >> (shift + 8)) == pfx);
                if (match) atomicAdd(&hist[(unsigned int)(key >> shift) & 255u], 1u);
            }
            __syncthreads();
            if (threadIdx.x == 0) {
                unsigned int cum = 0;
                int b = 0;
                for (; b < 255; b++) {
                    if (cum + hist[b] >= (unsigned int)need) break;
                    cum += hist[b];
                }
                sh_pfx = (pfx << 8) | (unsigned long long)(unsigned int)b;
                sh_need = need - (int)cum;
            }
            __syncthreads();
            pfx = sh_pfx;
            need = sh_need;
            __syncthreads();
        }
        theta = pfx;
    }
    __syncthreads();

    for (int i = threadIdx.x; i < n; i += 256) {
        unsigned int wb = __float_as_uint(cw[i]);
        unsigned long long key = (((unsigned long long)(~wb)) << 32) | (unsigned int)cs[i];
        if (key <= theta) {
            int ppos = atomicAdd(&sel_count[e], 1);
            sel_tok[e * CAP + ppos] = cs[i] >> 1;
            sel_w[e * CAP + ppos]  = cw[i];
            processed[cs[i] >> 1] = 1;
        }
    }
}

// ---------------- W [E][K][N] f32 -> Wt [E][N][K] bf16 (tiled transpose) ----------------
__global__ __launch_bounds__(256) void convert_wt_kernel(
    const float* __restrict__ W, u16* __restrict__ Wt, int K, int N)
{
    __shared__ float tile[64][65];
    const int e = blockIdx.z;
    const int k0 = blockIdx.y * 64, n0 = blockIdx.x * 64;
    const float* We = W + (size_t)e * K * N;
    u16* Wte = Wt + (size_t)e * N * K;
    const int tx = threadIdx.x & 63, ty = threadIdx.x >> 6;
    #pragma unroll
    for (int r = 0; r < 64; r += 4)
        tile[ty + r][tx] = We[(size_t)(k0 + ty + r) * N + n0 + tx];
    __syncthreads();
    #pragma unroll
    for (int r = 0; r < 64; r += 4) {
        int nn = ty + r;
        Wte[(size_t)(n0 + nn) * K + k0 + tx] = f2b(tile[tx][nn]);
    }
}

// ---------------- out = processed ? 0 : xn   (fused zero-init + passthrough) ----------------
__global__ __launch_bounds__(256) void init_out_kernel(
    const u16* __restrict__ xnb, const int* __restrict__ processed, float* __restrict__ out)
{
    size_t i = (size_t)blockIdx.x * 256 + threadIdx.x;   // float4 index over T*O/4
    int t = (int)(i >> 7);
    float4 v; v.x = 0.f; v.y = 0.f; v.z = 0.f; v.w = 0.f;
    if (!processed[t]) {
        const u16* xp = xnb + (i << 2);
        v.x = b2f(xp[0]); v.y = b2f(xp[1]); v.z = b2f(xp[2]); v.w = b2f(xp[3]);
    }
    ((float4*)out)[i] = v;
}

// ---------------- bf16 MFMA GEMM: 128x128 tile, BK=64, 4 waves, global_load_lds ----------------
// A [rows][K] bf16 (gathered via sel_tok when GATHER), Bt [N][K] bf16 (pre-transposed weights).
// EPI 0: h = bf16(gelu(acc + bias))   EPI 1: out[tok] += w * (acc + bias)
template<int GATHER, int EPI>
__global__ __launch_bounds__(256) void moe_gemm_kernel(
    const u16* __restrict__ A, const u16* __restrict__ Bt,
    const float* __restrict__ bias,
    const int* __restrict__ sel_tok_e, const float* __restrict__ sel_w_e,
    const int* __restrict__ sel_count, int e, int K, int N,
    u16* __restrict__ h_out, float* __restrict__ out)
{
    __shared__ u16 sA[128 * 64];
    __shared__ u16 sB[128 * 64];

    const int selc = sel_count[e];
    const int row0 = blockIdx.x * 128;
    if (row0 >= selc) return;
    const int n0 = blockIdx.y * 128;

    const int t = threadIdx.x;
    const int lane = t & 63;
    const int w = t >> 6;
    const int wm = (w >> 1) * 64, wn = (w & 1) * 64;
    const int lr = lane & 15;
    const int lg = lane >> 4;

    // staging geometry: inst i covers tile rows i*32 + t/8, 16B at k-offset (t%8)*8
    const int srow = t >> 3;
    const int sk   = (t & 7) * 8;

    const u16* asrc[4];
    #pragma unroll
    for (int i = 0; i < 4; i++) {
        int r = row0 + i * 32 + srow;
        int gr;
        if (GATHER) gr = (r < selc) ? sel_tok_e[r] : 0;
        else        gr = r;
        asrc[i] = A + (size_t)gr * K + sk;
    }
    const u16* bsrc[4];
    #pragma unroll
    for (int i = 0; i < 4; i++) {
        int nn = n0 + i * 32 + srow;
        bsrc[i] = Bt + (size_t)nn * K + sk;
    }

    f32x4 acc[4][4] = {};

    for (int k0 = 0; k0 < K; k0 += 64) {
        #pragma unroll
        for (int i = 0; i < 4; i++)
            gload_lds16(asrc[i] + k0, sA + i * 2048 + t * 8);
        #pragma unroll
        for (int i = 0; i < 4; i++)
            gload_lds16(bsrc[i] + k0, sB + i * 2048 + t * 8);
        asm volatile("s_waitcnt vmcnt(0)" ::: "memory");
        __syncthreads();

        #pragma unroll
        for (int kk = 0; kk < 64; kk += 32) {
            short8 af[4], bf[4];
            #pragma unroll
            for (int m = 0; m < 4; m++)
                af[m] = *(const short8*)&sA[(wm + m * 16 + lr) * 64 + kk + lg * 8];
            #pragma unroll
            for (int n = 0; n < 4; n++)
                bf[n] = *(const short8*)&sB[(wn + n * 16 + lr) * 64 + kk + lg * 8];
            #pragma unroll
            for (int m = 0; m < 4; m++)
                #pragma unroll
                for (int n = 0; n < 4; n++)
                    acc[m][n] = __builtin_amdgcn_mfma_f32_16x16x32_bf16(af[m], bf[n], acc[m][n], 0, 0, 0);
        }
        __syncthreads();
    }

    if (EPI == 0) {
        #pragma unroll
        for (int m = 0; m < 4; m++) {
            int row = row0 + wm + m * 16 + lg * 4;
            #pragma unroll
            for (int n = 0; n < 4; n++) {
                int col = n0 + wn + n * 16 + lr;
                float bb = bias[col];
                #pragma unroll
                for (int r = 0; r < 4; r++) {
                    float vv = acc[m][n][r] + bb;
                    float gel = 0.5f * vv * (1.0f + erff(vv * 0.70710678118654752440f));
                    h_out[(size_t)(row + r) * N + col] = f2b(gel);
                }
            }
        }
    } else {
        #pragma unroll
        for (int m = 0; m < 4; m++) {
            int row = row0 + wm + m * 16 + lg * 4;
            #pragma unroll
            for (int r = 0; r < 4; r++) {
                int rr = row + r;
                if (rr < selc) {
                    int tok = sel_tok_e[rr];
                    float wgt = sel_w_e[rr];
                    float* orow = out + (size_t)tok * O_DIM;
                    #pragma unroll
                    for (int n = 0; n < 4; n++) {
                        int col = n0 + wn + n * 16 + lr;
                        orow[col] += wgt * (acc[m][n][r] + bias[col]);
                    }
                }
            }
        }
    }
}

extern "C" void kernel_launch(void* const* d_in, const int* in_sizes, int n_in,
                              void* d_out, int out_size, void* d_ws, size_t ws_size,
                              hipStream_t stream) {
    const float* x     = (const float*)d_in[0];
    const float* noise = (const float*)d_in[1];
    const float* gamma = (const float*)d_in[2];
    const float* beta  = (const float*)d_in[3];
    const float* Wg    = (const float*)d_in[4];
    const float* bg    = (const float*)d_in[5];
    const float* W1    = (const float*)d_in[6];
    const float* b1    = (const float*)d_in[7];
    const float* W2    = (const float*)d_in[8];
    const float* b2    = (const float*)d_in[9];
    float* out = (float*)d_out;

    char* ws = (char*)d_ws;
    int*    counts    = (int*)(ws + OFF_COUNTS);
    int*    sel_count = (int*)(ws + OFF_SELC);
    int*    processed = (int*)(ws + OFF_PROC);
    float*  cand_w    = (float*)(ws + OFF_CANDW);
    int*    cand_slot = (int*)(ws + OFF_CANDS);
    int*    sel_tok   = (int*)(ws + OFF_SELTOK);
    float*  sel_w     = (float*)(ws + OFF_SELW);
    double* logits    = (double*)(ws + OFF_LOG);
    u16*    xnb       = (u16*)(ws + OFF_XNB);
    u16*    h         = (u16*)(ws + OFF_H);
    u16*    W1t       = (u16*)(ws + OFF_W1T);
    u16*    W2t       = (u16*)(ws + OFF_W2T);

    hipMemsetAsync(ws, 0, CTRL_BYTES, stream);
    hipMemsetAsync((char*)d_out + (size_t)T_TOKENS * O_DIM * 4, 0, 4, stream);  // aux_loss = 0

    convert_wt_kernel<<<dim3(H_DIM / 64, D_DIM / 64, E_NUM), 256, 0, stream>>>(W1, W1t, D_DIM, H_DIM);
    convert_wt_kernel<<<dim3(O_DIM / 64, H_DIM / 64, E_NUM), 256, 0, stream>>>(W2, W2t, H_DIM, O_DIM);

    ln_kernel<<<T_TOKENS / 4, 256, 0, stream>>>(x, gamma, beta, Wg, xnb, logits);
    gate_kernel<<<T_TOKENS / 256, 256, 0, stream>>>(logits, noise, bg, counts, cand_w, cand_slot);
    select_kernel<<<E_NUM, 256, 0, stream>>>(counts, cand_w, cand_slot, sel_count, sel_tok, sel_w, processed);
    init_out_kernel<<<(T_TOKENS * O_DIM / 4) / 256, 256, 0, stream>>>(xnb, processed, out);

    for (int e = 0; e < E_NUM; e++) {
        moe_gemm_kernel<1, 0><<<dim3(CAP / 128, H_DIM / 128), 256, 0, stream>>>(
            xnb, W1t + (size_t)e * H_DIM * D_DIM, b1 + (size_t)e * H_DIM,
            sel_tok + (size_t)e * CAP, sel_w + (size_t)e * CAP,
            sel_count, e, D_DIM, H_DIM, h, nullptr);
        moe_gemm_kernel<0, 1><<<dim3(CAP / 128, O_DIM / 128), 256, 0, stream>>>(
            h, W2t + (size_t)e * O_DIM * H_DIM, b2 + (size_t)e * O_DIM,
            sel_tok + (size_t)e * CAP, sel_w + (size_t)e * CAP,
            sel_count, e, H_DIM, O_DIM, nullptr, out);
    }
}

// Round 3
// 1266.050 us; speedup vs baseline: 5.7224x; 1.0350x over previous
//
#include <hip/hip_runtime.h>
#include <math.h>

typedef __attribute__((ext_vector_type(4))) float f32x4;
typedef __attribute__((ext_vector_type(8))) short short8;
typedef unsigned short u16;

#define T_TOKENS 65536
#define D_DIM    512
#define H_DIM    2048
#define O_DIM    512
#define E_NUM    8
#define CAP      8192

// ---- workspace layout (bytes) ----
static constexpr size_t OFF_COUNTS = 0;            // 8 ints
static constexpr size_t OFF_SELC   = 64;           // 8 ints
static constexpr size_t OFF_BNDC   = 128;          // 8 ints
static constexpr size_t OFF_PROC   = 192;          // T ints
static constexpr size_t OFF_HIST   = OFF_PROC + (size_t)T_TOKENS * 4;          // E*65536 uints (2MB)
static constexpr size_t CTRL_BYTES = OFF_HIST + (size_t)E_NUM * 65536 * 4;     // zeroed per launch (~2.36MB)
static constexpr size_t OFF_THR    = CTRL_BYTES;                                // 8 ints
static constexpr size_t OFF_REM    = OFF_THR + 64;                              // 8 ints
static constexpr size_t OFF_CANDW  = OFF_REM + 64;
static constexpr size_t OFF_CANDS  = OFF_CANDW + (size_t)E_NUM * T_TOKENS * 4;  // +2MB
static constexpr size_t OFF_SELTOK = OFF_CANDS + (size_t)E_NUM * T_TOKENS * 4;  // +2MB
static constexpr size_t OFF_SELW   = OFF_SELTOK + (size_t)E_NUM * CAP * 4;      // +256KB
static constexpr size_t OFF_LOG    = OFF_SELW + (size_t)E_NUM * CAP * 4;        // +256KB, 4MB region
// bnd arrays overlap the logits region (logits dead before emit runs)
static constexpr size_t OFF_BNDS   = OFF_LOG;                                   // E*CAP ints (256KB)
static constexpr size_t OFF_BNDW   = OFF_LOG + (size_t)E_NUM * CAP * 4 * 4;     // E*CAP floats (spaced)
static constexpr size_t OFF_XNB    = OFF_LOG + (size_t)T_TOKENS * E_NUM * 8;    // +4MB
static constexpr size_t OFF_H      = OFF_XNB + (size_t)T_TOKENS * D_DIM * 2;    // +64MB
static constexpr size_t OFF_W1T    = OFF_H + (size_t)CAP * H_DIM * 2;           // +32MB
static constexpr size_t OFF_W2T    = OFF_W1T + (size_t)E_NUM * H_DIM * D_DIM * 2;// +16MB
// end = OFF_W2T + 16MB ~= 139MB total

__device__ __forceinline__ u16 f2b(float f) {            // f32 -> bf16 RNE
    unsigned u = __float_as_uint(f);
    unsigned r = (u + 0x7FFFu + ((u >> 16) & 1u)) >> 16;
    return (u16)r;
}
__device__ __forceinline__ float b2f(u16 b) {
    return __uint_as_float(((unsigned)b) << 16);
}

#define AS1 __attribute__((address_space(1)))
#define AS3 __attribute__((address_space(3)))
__device__ __forceinline__ void gload_lds16(const void* g, void* l) {
    __builtin_amdgcn_global_load_lds((const AS1 void*)g, (AS3 void*)l, 16, 0, 0);
}

// ---------------- LayerNorm + fp64 logits ----------------
__global__ __launch_bounds__(256) void ln_kernel(
    const float* __restrict__ x, const float* __restrict__ gamma,
    const float* __restrict__ beta, const float* __restrict__ Wg,
    u16* __restrict__ xnb, double* __restrict__ logits)
{
    __shared__ float sWg[E_NUM * D_DIM];
    for (int i = threadIdx.x; i < E_NUM * D_DIM; i += 256) sWg[i] = Wg[i];
    __syncthreads();

    const int wave = threadIdx.x >> 6, lane = threadIdx.x & 63;
    const int t = blockIdx.x * 4 + wave;
    const float* xr = x + (size_t)t * D_DIM;

    float xv[8];
    #pragma unroll
    for (int i = 0; i < 8; i++) xv[i] = xr[i * 64 + lane];

    double s = 0.0;
    #pragma unroll
    for (int i = 0; i < 8; i++) s += (double)xv[i];
    #pragma unroll
    for (int o = 32; o > 0; o >>= 1) s += __shfl_xor(s, o);
    double mu = s / 512.0;

    double v = 0.0;
    #pragma unroll
    for (int i = 0; i < 8; i++) { double d = (double)xv[i] - mu; v += d * d; }
    #pragma unroll
    for (int o = 32; o > 0; o >>= 1) v += __shfl_xor(v, o);
    double rstd = 1.0 / sqrt(v / 512.0 + 1e-5);

    float xnf[8];
    #pragma unroll
    for (int i = 0; i < 8; i++) {
        int c = i * 64 + lane;
        double xd = ((double)xv[i] - mu) * rstd * (double)gamma[c] + (double)beta[c];
        xnf[i] = (float)xd;
        xnb[(size_t)t * D_DIM + c] = f2b(xnf[i]);
    }

    double p[E_NUM];
    #pragma unroll
    for (int e = 0; e < E_NUM; e++) p[e] = 0.0;
    #pragma unroll
    for (int i = 0; i < 8; i++) {
        int c = i * 64 + lane;
        double xd = (double)xnf[i];
        #pragma unroll
        for (int e = 0; e < E_NUM; e++) p[e] += xd * (double)sWg[e * D_DIM + c];
    }
    #pragma unroll
    for (int o = 32; o > 0; o >>= 1) {
        #pragma unroll
        for (int e = 0; e < E_NUM; e++) p[e] += __shfl_xor(p[e], o);
    }
    if (lane < 8) {
        double vv = p[0];
        #pragma unroll
        for (int e = 1; e < 8; e++) if (lane == e) vv = p[e];
        logits[(size_t)t * 8 + lane] = vv;
    }
}

// ---------------- gate: softmax + top2 + normalize + 16b-prefix histogram ----------------
__global__ __launch_bounds__(256) void gate_kernel(
    const double* __restrict__ logits, const float* __restrict__ noise,
    const float* __restrict__ bg,
    int* __restrict__ counts, float* __restrict__ cand_w, int* __restrict__ cand_slot,
    unsigned int* __restrict__ hist)
{
    __shared__ int lcnt[E_NUM], lbase[E_NUM];
    if (threadIdx.x < E_NUM) lcnt[threadIdx.x] = 0;
    __syncthreads();
    const int t = blockIdx.x * 256 + threadIdx.x;

    double l[E_NUM], m = -1e300;
    #pragma unroll
    for (int e = 0; e < E_NUM; e++) {
        l[e] = logits[(size_t)t * 8 + e] + (double)bg[e] + 0.125 * (double)noise[(size_t)t * 8 + e];
        if (l[e] > m) m = l[e];
    }
    double sum = 0.0, g[E_NUM];
    #pragma unroll
    for (int e = 0; e < E_NUM; e++) { g[e] = exp(l[e] - m); sum += g[e]; }
    double inv = 1.0 / sum;
    #pragma unroll
    for (int e = 0; e < E_NUM; e++) g[e] *= inv;

    double v1 = -1.0; int i1 = 0;
    #pragma unroll
    for (int e = 0; e < E_NUM; e++) if (g[e] > v1) { v1 = g[e]; i1 = e; }
    double v2 = -1.0; int i2 = 0;
    #pragma unroll
    for (int e = 0; e < E_NUM; e++) if (e != i1 && g[e] > v2) { v2 = g[e]; i2 = e; }

    double denom = v1 + v2 + 1e-20;
    float w1 = (float)(v1 / denom);
    float w2 = (float)(v2 / denom);

    atomicAdd(&hist[(size_t)i1 * 65536 + ((~__float_as_uint(w1)) >> 16)], 1u);
    atomicAdd(&hist[(size_t)i2 * 65536 + ((~__float_as_uint(w2)) >> 16)], 1u);

    int p1 = atomicAdd(&lcnt[i1], 1);
    int p2 = atomicAdd(&lcnt[i2], 1);
    __syncthreads();
    if (threadIdx.x < E_NUM) lbase[threadIdx.x] = atomicAdd(&counts[threadIdx.x], lcnt[threadIdx.x]);
    __syncthreads();
    cand_w[(size_t)i1 * T_TOKENS + lbase[i1] + p1] = w1;
    cand_slot[(size_t)i1 * T_TOKENS + lbase[i1] + p1] = 2 * t;
    cand_w[(size_t)i2 * T_TOKENS + lbase[i2] + p2] = w2;
    cand_slot[(size_t)i2 * T_TOKENS + lbase[i2] + p2] = 2 * t + 1;
}

// ---------------- scan: find 16-bit threshold bin + residual need per expert ----------------
__global__ __launch_bounds__(1024) void scan_kernel(
    const unsigned int* __restrict__ hist, const int* __restrict__ counts,
    int* __restrict__ thr16, int* __restrict__ rem)
{
    const int e = blockIdx.x;
    const int n = counts[e];
    if (n <= CAP) {
        if (threadIdx.x == 0) { thr16[e] = 65536; rem[e] = 0; }
        return;
    }
    const unsigned int* h = hist + (size_t)e * 65536;
    __shared__ unsigned int part[1024];
    const int tid = threadIdx.x;
    unsigned int own = 0;
    const int base = tid * 64;
    #pragma unroll 8
    for (int i = 0; i < 64; i++) own += h[base + i];
    part[tid] = own;
    __syncthreads();
    for (int off = 1; off < 1024; off <<= 1) {
        unsigned int v = (tid >= off) ? part[tid - off] : 0u;
        __syncthreads();
        part[tid] += v;
        __syncthreads();
    }
    unsigned int incl = part[tid];
    unsigned int excl = incl - own;
    const unsigned int need = CAP;
    if (excl < need && incl >= need) {
        unsigned int cum = excl;
        for (int i = 0; i < 64; i++) {
            unsigned int hv = h[base + i];
            if (cum + hv >= need) { thr16[e] = base + i; rem[e] = (int)(need - cum); break; }
            cum += hv;
        }
    }
}

// ---------------- emit: select below-threshold candidates, collect boundary bin ----------------
__global__ __launch_bounds__(256) void emit_kernel(
    const int* __restrict__ counts, const float* __restrict__ cand_w,
    const int* __restrict__ cand_slot, const int* __restrict__ thr16,
    int* __restrict__ sel_count, int* __restrict__ sel_tok, float* __restrict__ sel_w,
    int* __restrict__ bnd_count, int* __restrict__ bnd_slot, float* __restrict__ bnd_w,
    int* __restrict__ processed)
{
    const int e = blockIdx.y;
    const int n = counts[e];
    const int thr = thr16[e];
    const float* cw = cand_w + (size_t)e * T_TOKENS;
    const int* cs = cand_slot + (size_t)e * T_TOKENS;
    for (int i = blockIdx.x * 256 + threadIdx.x; i < n; i += gridDim.x * 256) {
        float w = cw[i];
        int slot = cs[i];
        int p16 = (int)((~__float_as_uint(w)) >> 16);
        if (p16 < thr) {
            int pos = atomicAdd(&sel_count[e], 1);
            sel_tok[e * CAP + pos] = slot >> 1;
            sel_w[e * CAP + pos]  = w;
            processed[slot >> 1] = 1;
        } else if (p16 == thr) {
            int bpos = atomicAdd(&bnd_count[e], 1);
            bnd_slot[(size_t)e * CAP * 4 + bpos] = slot;
            bnd_w[(size_t)e * CAP * 4 + bpos]   = w;
        }
    }
}

// ---------------- boundary: exact rank among boundary-bin candidates ----------------
__global__ __launch_bounds__(256) void boundary_kernel(
    const int* __restrict__ bnd_count, const int* __restrict__ bnd_slot,
    const float* __restrict__ bnd_w, const int* __restrict__ rem,
    int* __restrict__ sel_count, int* __restrict__ sel_tok, float* __restrict__ sel_w,
    int* __restrict__ processed)
{
    const int e = blockIdx.x;
    const int r = rem[e];
    if (r == 0) return;
    const int nb = bnd_count[e];
    const int* bs = bnd_slot + (size_t)e * CAP * 4;
    const float* bw = bnd_w + (size_t)e * CAP * 4;
    for (int i = threadIdx.x; i < nb; i += 256) {
        unsigned long long ki = (((unsigned long long)(~__float_as_uint(bw[i]))) << 32) | (unsigned int)bs[i];
        int rank = 0;
        for (int j = 0; j < nb; j++) {
            unsigned long long kj = (((unsigned long long)(~__float_as_uint(bw[j]))) << 32) | (unsigned int)bs[j];
            rank += (kj < ki);
        }
        if (rank < r) {
            int pos = atomicAdd(&sel_count[e], 1);
            sel_tok[e * CAP + pos] = bs[i] >> 1;
            sel_w[e * CAP + pos]  = bw[i];
            processed[bs[i] >> 1] = 1;
        }
    }
}

// ---------------- W [E][K][N] f32 -> Wt [E][N][K] bf16 (tiled transpose) ----------------
__global__ __launch_bounds__(256) void convert_wt_kernel(
    const float* __restrict__ W, u16* __restrict__ Wt, int K, int N)
{
    __shared__ float tile[64][65];
    const int e = blockIdx.z;
    const int k0 = blockIdx.y * 64, n0 = blockIdx.x * 64;
    const float* We = W + (size_t)e * K * N;
    u16* Wte = Wt + (size_t)e * N * K;
    const int tx = threadIdx.x & 63, ty = threadIdx.x >> 6;
    #pragma unroll
    for (int r = 0; r < 64; r += 4)
        tile[ty + r][tx] = We[(size_t)(k0 + ty + r) * N + n0 + tx];
    __syncthreads();
    #pragma unroll
    for (int r = 0; r < 64; r += 4) {
        int nn = ty + r;
        Wte[(size_t)(n0 + nn) * K + k0 + tx] = f2b(tile[tx][nn]);
    }
}

// ---------------- out = processed ? 0 : xn ----------------
__global__ __launch_bounds__(256) void init_out_kernel(
    const u16* __restrict__ xnb, const int* __restrict__ processed, float* __restrict__ out)
{
    size_t i = (size_t)blockIdx.x * 256 + threadIdx.x;
    int t = (int)(i >> 7);
    float4 v; v.x = 0.f; v.y = 0.f; v.z = 0.f; v.w = 0.f;
    if (!processed[t]) {
        const u16* xp = xnb + (i << 2);
        v.x = b2f(xp[0]); v.y = b2f(xp[1]); v.z = b2f(xp[2]); v.w = b2f(xp[3]);
    }
    ((float4*)out)[i] = v;
}

// ---------------- bf16 MFMA GEMM: 128x128 tile, BK=64, 4 waves, global_load_lds ----------------
template<int GATHER, int EPI>
__global__ __launch_bounds__(256) void moe_gemm_kernel(
    const u16* __restrict__ A, const u16* __restrict__ Bt,
    const float* __restrict__ bias,
    const int* __restrict__ sel_tok_e, const float* __restrict__ sel_w_e,
    const int* __restrict__ sel_count, int e, int K, int N,
    u16* __restrict__ h_out, float* __restrict__ out)
{
    __shared__ u16 sA[128 * 64];
    __shared__ u16 sB[128 * 64];

    const int selc = sel_count[e];
    const int row0 = blockIdx.x * 128;
    if (row0 >= selc) return;
    const int n0 = blockIdx.y * 128;

    const int t = threadIdx.x;
    const int lane = t & 63;
    const int w = t >> 6;
    const int wm = (w >> 1) * 64, wn = (w & 1) * 64;
    const int lr = lane & 15;
    const int lg = lane >> 4;

    const int srow = t >> 3;
    const int sk   = (t & 7) * 8;

    const u16* asrc[4];
    #pragma unroll
    for (int i = 0; i < 4; i++) {
        int r = row0 + i * 32 + srow;
        int gr;
        if (GATHER) gr = (r < selc) ? sel_tok_e[r] : 0;
        else        gr = r;
        asrc[i] = A + (size_t)gr * K + sk;
    }
    const u16* bsrc[4];
    #pragma unroll
    for (int i = 0; i < 4; i++) {
        int nn = n0 + i * 32 + srow;
        bsrc[i] = Bt + (size_t)nn * K + sk;
    }

    f32x4 acc[4][4] = {};

    for (int k0 = 0; k0 < K; k0 += 64) {
        #pragma unroll
        for (int i = 0; i < 4; i++)
            gload_lds16(asrc[i] + k0, sA + i * 2048 + t * 8);
        #pragma unroll
        for (int i = 0; i < 4; i++)
            gload_lds16(bsrc[i] + k0, sB + i * 2048 + t * 8);
        asm volatile("s_waitcnt vmcnt(0)" ::: "memory");
        __syncthreads();

        #pragma unroll
        for (int kk = 0; kk < 64; kk += 32) {
            short8 af[4], bf[4];
            #pragma unroll
            for (int m = 0; m < 4; m++)
                af[m] = *(const short8*)&sA[(wm + m * 16 + lr) * 64 + kk + lg * 8];
            #pragma unroll
            for (int n = 0; n < 4; n++)
                bf[n] = *(const short8*)&sB[(wn + n * 16 + lr) * 64 + kk + lg * 8];
            #pragma unroll
            for (int m = 0; m < 4; m++)
                #pragma unroll
                for (int n = 0; n < 4; n++)
                    acc[m][n] = __builtin_amdgcn_mfma_f32_16x16x32_bf16(af[m], bf[n], acc[m][n], 0, 0, 0);
        }
        __syncthreads();
    }

    if (EPI == 0) {
        #pragma unroll
        for (int m = 0; m < 4; m++) {
            int row = row0 + wm + m * 16 + lg * 4;
            #pragma unroll
            for (int n = 0; n < 4; n++) {
                int col = n0 + wn + n * 16 + lr;
                float bb = bias[col];
                #pragma unroll
                for (int r = 0; r < 4; r++) {
                    float vv = acc[m][n][r] + bb;
                    float gel = 0.5f * vv * (1.0f + erff(vv * 0.70710678118654752440f));
                    h_out[(size_t)(row + r) * N + col] = f2b(gel);
                }
            }
        }
    } else {
        #pragma unroll
        for (int m = 0; m < 4; m++) {
            int row = row0 + wm + m * 16 + lg * 4;
            #pragma unroll
            for (int r = 0; r < 4; r++) {
                int rr = row + r;
                if (rr < selc) {
                    int tok = sel_tok_e[rr];
                    float wgt = sel_w_e[rr];
                    float* orow = out + (size_t)tok * O_DIM;
                    #pragma unroll
                    for (int n = 0; n < 4; n++) {
                        int col = n0 + wn + n * 16 + lr;
                        orow[col] += wgt * (acc[m][n][r] + bias[col]);
                    }
                }
            }
        }
    }
}

extern "C" void kernel_launch(void* const* d_in, const int* in_sizes, int n_in,
                              void* d_out, int out_size, void* d_ws, size_t ws_size,
                              hipStream_t stream) {
    const float* x     = (const float*)d_in[0];
    const float* noise = (const float*)d_in[1];
    const float* gamma = (const float*)d_in[2];
    const float* beta  = (const float*)d_in[3];
    const float* Wg    = (const float*)d_in[4];
    const float* bg    = (const float*)d_in[5];
    const float* W1    = (const float*)d_in[6];
    const float* b1    = (const float*)d_in[7];
    const float* W2    = (const float*)d_in[8];
    const float* b2    = (const float*)d_in[9];
    float* out = (float*)d_out;

    char* ws = (char*)d_ws;
    int*    counts    = (int*)(ws + OFF_COUNTS);
    int*    sel_count = (int*)(ws + OFF_SELC);
    int*    bnd_count = (int*)(ws + OFF_BNDC);
    int*    processed = (int*)(ws + OFF_PROC);
    unsigned int* hist = (unsigned int*)(ws + OFF_HIST);
    int*    thr16     = (int*)(ws + OFF_THR);
    int*    rem       = (int*)(ws + OFF_REM);
    float*  cand_w    = (float*)(ws + OFF_CANDW);
    int*    cand_slot = (int*)(ws + OFF_CANDS);
    int*    sel_tok   = (int*)(ws + OFF_SELTOK);
    float*  sel_w     = (float*)(ws + OFF_SELW);
    double* logits    = (double*)(ws + OFF_LOG);
    int*    bnd_slot  = (int*)(ws + OFF_BNDS);
    float*  bnd_w     = (float*)(ws + OFF_BNDW);
    u16*    xnb       = (u16*)(ws + OFF_XNB);
    u16*    h         = (u16*)(ws + OFF_H);
    u16*    W1t       = (u16*)(ws + OFF_W1T);
    u16*    W2t       = (u16*)(ws + OFF_W2T);

    hipMemsetAsync(ws, 0, CTRL_BYTES, stream);
    hipMemsetAsync((char*)d_out + (size_t)T_TOKENS * O_DIM * 4, 0, 4, stream);  // aux_loss = 0

    convert_wt_kernel<<<dim3(H_DIM / 64, D_DIM / 64, E_NUM), 256, 0, stream>>>(W1, W1t, D_DIM, H_DIM);
    convert_wt_kernel<<<dim3(O_DIM / 64, H_DIM / 64, E_NUM), 256, 0, stream>>>(W2, W2t, H_DIM, O_DIM);

    ln_kernel<<<T_TOKENS / 4, 256, 0, stream>>>(x, gamma, beta, Wg, xnb, logits);
    gate_kernel<<<T_TOKENS / 256, 256, 0, stream>>>(logits, noise, bg, counts, cand_w, cand_slot, hist);
    scan_kernel<<<E_NUM, 1024, 0, stream>>>(hist, counts, thr16, rem);
    emit_kernel<<<dim3(64, E_NUM), 256, 0, stream>>>(counts, cand_w, cand_slot, thr16,
                                                     sel_count, sel_tok, sel_w,
                                                     bnd_count, bnd_slot, bnd_w, processed);
    boundary_kernel<<<E_NUM, 256, 0, stream>>>(bnd_count, bnd_slot, bnd_w, rem,
                                               sel_count, sel_tok, sel_w, processed);
    init_out_kernel<<<(T_TOKENS * O_DIM / 4) / 256, 256, 0, stream>>>(xnb, processed, out);

    for (int e = 0; e < E_NUM; e++) {
        moe_gemm_kernel<1, 0><<<dim3(CAP / 128, H_DIM / 128), 256, 0, stream>>>(
            xnb, W1t + (size_t)e * H_DIM * D_DIM, b1 + (size_t)e * H_DIM,
            sel_tok + (size_t)e * CAP, sel_w + (size_t)e * CAP,
            sel_count, e, D_DIM, H_DIM, h, nullptr);
        moe_gemm_kernel<0, 1><<<dim3(CAP / 128, O_DIM / 128), 256, 0, stream>>>(
            h, W2t + (size_t)e * O_DIM * H_DIM, b2 + (size_t)e * O_DIM,
            sel_tok + (size_t)e * CAP, sel_w + (size_t)e * CAP,
            sel_count, e, H_DIM, O_DIM, nullptr, out);
    }
}

// Round 4
// 1086.293 us; speedup vs baseline: 6.6694x; 1.1655x over previous
//
#include <hip/hip_runtime.h>
#include <math.h>

typedef __attribute__((ext_vector_type(4))) float f32x4;
typedef __attribute__((ext_vector_type(8))) short short8;
typedef unsigned short u16;

#define T_TOKENS 65536
#define D_DIM    512
#define H_DIM    2048
#define O_DIM    512
#define E_NUM    8
#define CAP      8192

// ---- workspace layout (bytes) ----
static constexpr size_t OFF_COUNTS = 0;            // 8 ints
static constexpr size_t OFF_SELC   = 64;           // 8 ints
static constexpr size_t OFF_BNDC   = 128;          // 8 ints
static constexpr size_t OFF_PROC   = 192;          // T ints
static constexpr size_t OFF_HIST   = OFF_PROC + (size_t)T_TOKENS * 4;          // E*65536 uints (2MB)
static constexpr size_t CTRL_BYTES = OFF_HIST + (size_t)E_NUM * 65536 * 4;     // zeroed per launch
static constexpr size_t OFF_THR    = CTRL_BYTES;                               // 8 ints
static constexpr size_t OFF_REM    = OFF_THR + 64;                             // 8 ints
static constexpr size_t OFF_CANDW  = OFF_REM + 64;
static constexpr size_t OFF_CANDS  = OFF_CANDW + (size_t)E_NUM * T_TOKENS * 4; // +2MB
static constexpr size_t OFF_SELTOK = OFF_CANDS + (size_t)E_NUM * T_TOKENS * 4; // +2MB
static constexpr size_t OFF_SELW   = OFF_SELTOK + (size_t)E_NUM * CAP * 4;     // +256KB
static constexpr size_t OFF_LOG    = OFF_SELW + (size_t)E_NUM * CAP * 4;       // +256KB, 4MB region
// bnd arrays overlap logits region (logits dead before emit runs)
static constexpr size_t OFF_BNDS   = OFF_LOG;                                  // 1MB
static constexpr size_t OFF_BNDW   = OFF_LOG + (size_t)E_NUM * CAP * 4 * 4;    // 1MB
static constexpr size_t OFF_XNB    = OFF_LOG + (size_t)T_TOKENS * E_NUM * 8;   // +4MB
static constexpr size_t OFF_W1T    = OFF_XNB + (size_t)T_TOKENS * D_DIM * 2;   // +64MB
static constexpr size_t OFF_W2T    = OFF_W1T + (size_t)E_NUM * D_DIM * H_DIM * 2; // +16MB
static constexpr size_t OFF_H      = OFF_W2T + (size_t)E_NUM * H_DIM * O_DIM * 2; // +16MB
static constexpr size_t NEED_SMALL = OFF_H + (size_t)CAP * H_DIM * 2;             // ~139MB
static constexpr size_t NEED_BIG   = OFF_H + (size_t)E_NUM * CAP * H_DIM * 2;     // ~363MB

__device__ __forceinline__ u16 f2b(float f) {            // f32 -> bf16 RNE
    unsigned u = __float_as_uint(f);
    unsigned r = (u + 0x7FFFu + ((u >> 16) & 1u)) >> 16;
    return (u16)r;
}
__device__ __forceinline__ float b2f(u16 b) {
    return __uint_as_float(((unsigned)b) << 16);
}

#define AS1 __attribute__((address_space(1)))
#define AS3 __attribute__((address_space(3)))
__device__ __forceinline__ void gload_lds16(const void* g, void* l) {
    __builtin_amdgcn_global_load_lds((const AS1 void*)g, (AS3 void*)l, 16, 0, 0);
}

// ---------------- LayerNorm + fp64 logits (grid-stride: 64 tokens/block) ----------------
__global__ __launch_bounds__(256) void ln_kernel(
    const float* __restrict__ x, const float* __restrict__ gamma,
    const float* __restrict__ beta, const float* __restrict__ Wg,
    u16* __restrict__ xnb, double* __restrict__ logits)
{
    __shared__ float sWg[E_NUM * D_DIM];
    for (int i = threadIdx.x; i < E_NUM * D_DIM; i += 256) sWg[i] = Wg[i];
    __syncthreads();

    const int wave = threadIdx.x >> 6, lane = threadIdx.x & 63;

    for (int it = 0; it < 16; ++it) {
        const int t = blockIdx.x * 64 + it * 4 + wave;
        const float* xr = x + (size_t)t * D_DIM;

        float xv[8];
        #pragma unroll
        for (int i = 0; i < 8; i++) xv[i] = xr[i * 64 + lane];

        double s = 0.0;
        #pragma unroll
        for (int i = 0; i < 8; i++) s += (double)xv[i];
        #pragma unroll
        for (int o = 32; o > 0; o >>= 1) s += __shfl_xor(s, o);
        double mu = s / 512.0;

        double v = 0.0;
        #pragma unroll
        for (int i = 0; i < 8; i++) { double d = (double)xv[i] - mu; v += d * d; }
        #pragma unroll
        for (int o = 32; o > 0; o >>= 1) v += __shfl_xor(v, o);
        double rstd = 1.0 / sqrt(v / 512.0 + 1e-5);

        float xnf[8];
        #pragma unroll
        for (int i = 0; i < 8; i++) {
            int c = i * 64 + lane;
            double xd = ((double)xv[i] - mu) * rstd * (double)gamma[c] + (double)beta[c];
            xnf[i] = (float)xd;
            xnb[(size_t)t * D_DIM + c] = f2b(xnf[i]);
        }

        double p[E_NUM];
        #pragma unroll
        for (int e = 0; e < E_NUM; e++) p[e] = 0.0;
        #pragma unroll
        for (int i = 0; i < 8; i++) {
            int c = i * 64 + lane;
            double xd = (double)xnf[i];
            #pragma unroll
            for (int e = 0; e < E_NUM; e++) p[e] += xd * (double)sWg[e * D_DIM + c];
        }
        #pragma unroll
        for (int o = 32; o > 0; o >>= 1) {
            #pragma unroll
            for (int e = 0; e < E_NUM; e++) p[e] += __shfl_xor(p[e], o);
        }
        if (lane < 8) {
            double vv = p[0];
            #pragma unroll
            for (int e = 1; e < 8; e++) if (lane == e) vv = p[e];
            logits[(size_t)t * 8 + lane] = vv;
        }
    }
}

// ---------------- gate: softmax + top2 + normalize + 16b-prefix histogram ----------------
__global__ __launch_bounds__(256) void gate_kernel(
    const double* __restrict__ logits, const float* __restrict__ noise,
    const float* __restrict__ bg,
    int* __restrict__ counts, float* __restrict__ cand_w, int* __restrict__ cand_slot,
    unsigned int* __restrict__ hist)
{
    __shared__ int lcnt[E_NUM], lbase[E_NUM];
    if (threadIdx.x < E_NUM) lcnt[threadIdx.x] = 0;
    __syncthreads();
    const int t = blockIdx.x * 256 + threadIdx.x;

    double l[E_NUM], m = -1e300;
    #pragma unroll
    for (int e = 0; e < E_NUM; e++) {
        l[e] = logits[(size_t)t * 8 + e] + (double)bg[e] + 0.125 * (double)noise[(size_t)t * 8 + e];
        if (l[e] > m) m = l[e];
    }
    double sum = 0.0, g[E_NUM];
    #pragma unroll
    for (int e = 0; e < E_NUM; e++) { g[e] = exp(l[e] - m); sum += g[e]; }
    double inv = 1.0 / sum;
    #pragma unroll
    for (int e = 0; e < E_NUM; e++) g[e] *= inv;

    double v1 = -1.0; int i1 = 0;
    #pragma unroll
    for (int e = 0; e < E_NUM; e++) if (g[e] > v1) { v1 = g[e]; i1 = e; }
    double v2 = -1.0; int i2 = 0;
    #pragma unroll
    for (int e = 0; e < E_NUM; e++) if (e != i1 && g[e] > v2) { v2 = g[e]; i2 = e; }

    double denom = v1 + v2 + 1e-20;
    float w1 = (float)(v1 / denom);
    float w2 = (float)(v2 / denom);

    atomicAdd(&hist[(size_t)i1 * 65536 + ((~__float_as_uint(w1)) >> 16)], 1u);
    atomicAdd(&hist[(size_t)i2 * 65536 + ((~__float_as_uint(w2)) >> 16)], 1u);

    int p1 = atomicAdd(&lcnt[i1], 1);
    int p2 = atomicAdd(&lcnt[i2], 1);
    __syncthreads();
    if (threadIdx.x < E_NUM) lbase[threadIdx.x] = atomicAdd(&counts[threadIdx.x], lcnt[threadIdx.x]);
    __syncthreads();
    cand_w[(size_t)i1 * T_TOKENS + lbase[i1] + p1] = w1;
    cand_slot[(size_t)i1 * T_TOKENS + lbase[i1] + p1] = 2 * t;
    cand_w[(size_t)i2 * T_TOKENS + lbase[i2] + p2] = w2;
    cand_slot[(size_t)i2 * T_TOKENS + lbase[i2] + p2] = 2 * t + 1;
}

// ---------------- scan: find 16-bit threshold bin + residual need per expert ----------------
__global__ __launch_bounds__(1024) void scan_kernel(
    const unsigned int* __restrict__ hist, const int* __restrict__ counts,
    int* __restrict__ thr16, int* __restrict__ rem)
{
    const int e = blockIdx.x;
    const int n = counts[e];
    if (n <= CAP) {
        if (threadIdx.x == 0) { thr16[e] = 65536; rem[e] = 0; }
        return;
    }
    const unsigned int* h = hist + (size_t)e * 65536;
    __shared__ unsigned int part[1024];
    const int tid = threadIdx.x;
    unsigned int own = 0;
    const int base = tid * 64;
    #pragma unroll 8
    for (int i = 0; i < 64; i++) own += h[base + i];
    part[tid] = own;
    __syncthreads();
    for (int off = 1; off < 1024; off <<= 1) {
        unsigned int v = (tid >= off) ? part[tid - off] : 0u;
        __syncthreads();
        part[tid] += v;
        __syncthreads();
    }
    unsigned int incl = part[tid];
    unsigned int excl = incl - own;
    const unsigned int need = CAP;
    if (excl < need && incl >= need) {
        unsigned int cum = excl;
        for (int i = 0; i < 64; i++) {
            unsigned int hv = h[base + i];
            if (cum + hv >= need) { thr16[e] = base + i; rem[e] = (int)(need - cum); break; }
            cum += hv;
        }
    }
}

// ---------------- emit: select below-threshold candidates, collect boundary bin ----------------
__global__ __launch_bounds__(256) void emit_kernel(
    const int* __restrict__ counts, const float* __restrict__ cand_w,
    const int* __restrict__ cand_slot, const int* __restrict__ thr16,
    int* __restrict__ sel_count, int* __restrict__ sel_tok, float* __restrict__ sel_w,
    int* __restrict__ bnd_count, int* __restrict__ bnd_slot, float* __restrict__ bnd_w,
    int* __restrict__ processed)
{
    const int e = blockIdx.y;
    const int n = counts[e];
    const int thr = thr16[e];
    const float* cw = cand_w + (size_t)e * T_TOKENS;
    const int* cs = cand_slot + (size_t)e * T_TOKENS;
    for (int i = blockIdx.x * 256 + threadIdx.x; i < n; i += gridDim.x * 256) {
        float w = cw[i];
        int slot = cs[i];
        int p16 = (int)((~__float_as_uint(w)) >> 16);
        if (p16 < thr) {
            int pos = atomicAdd(&sel_count[e], 1);
            sel_tok[e * CAP + pos] = slot >> 1;
            sel_w[e * CAP + pos]  = w;
            processed[slot >> 1] = 1;
        } else if (p16 == thr) {
            int bpos = atomicAdd(&bnd_count[e], 1);
            bnd_slot[(size_t)e * CAP * 4 + bpos] = slot;
            bnd_w[(size_t)e * CAP * 4 + bpos]   = w;
        }
    }
}

// ---------------- boundary: exact rank among boundary-bin candidates ----------------
__global__ __launch_bounds__(256) void boundary_kernel(
    const int* __restrict__ bnd_count, const int* __restrict__ bnd_slot,
    const float* __restrict__ bnd_w, const int* __restrict__ rem,
    int* __restrict__ sel_count, int* __restrict__ sel_tok, float* __restrict__ sel_w,
    int* __restrict__ processed)
{
    const int e = blockIdx.x;
    const int r = rem[e];
    if (r == 0) return;
    const int nb = bnd_count[e];
    const int* bs = bnd_slot + (size_t)e * CAP * 4;
    const float* bw = bnd_w + (size_t)e * CAP * 4;
    for (int i = threadIdx.x; i < nb; i += 256) {
        unsigned long long ki = (((unsigned long long)(~__float_as_uint(bw[i]))) << 32) | (unsigned int)bs[i];
        int rank = 0;
        for (int j = 0; j < nb; j++) {
            unsigned long long kj = (((unsigned long long)(~__float_as_uint(bw[j]))) << 32) | (unsigned int)bs[j];
            rank += (kj < ki);
        }
        if (rank < r) {
            int pos = atomicAdd(&sel_count[e], 1);
            sel_tok[e * CAP + pos] = bs[i] >> 1;
            sel_w[e * CAP + pos]  = bw[i];
            processed[bs[i] >> 1] = 1;
        }
    }
}

// ---------------- W [E][K][N] f32 -> Wt [E][N][K] bf16 (tiled transpose) ----------------
__global__ __launch_bounds__(256) void convert_wt_kernel(
    const float* __restrict__ W, u16* __restrict__ Wt, int K, int N)
{
    __shared__ float tile[64][65];
    const int e = blockIdx.z;
    const int k0 = blockIdx.y * 64, n0 = blockIdx.x * 64;
    const float* We = W + (size_t)e * K * N;
    u16* Wte = Wt + (size_t)e * N * K;
    const int tx = threadIdx.x & 63, ty = threadIdx.x >> 6;
    #pragma unroll
    for (int r = 0; r < 64; r += 4)
        tile[ty + r][tx] = We[(size_t)(k0 + ty + r) * N + n0 + tx];
    __syncthreads();
    #pragma unroll
    for (int r = 0; r < 64; r += 4) {
        int nn = ty + r;
        Wte[(size_t)(n0 + nn) * K + k0 + tx] = f2b(tile[tx][nn]);
    }
}

// ---------------- out = processed ? 0 : xn ----------------
__global__ __launch_bounds__(256) void init_out_kernel(
    const u16* __restrict__ xnb, const int* __restrict__ processed, float* __restrict__ out)
{
    size_t i = (size_t)blockIdx.x * 256 + threadIdx.x;
    int t = (int)(i >> 7);
    float4 v; v.x = 0.f; v.y = 0.f; v.z = 0.f; v.w = 0.f;
    if (!processed[t]) {
        const u16* xp = xnb + (i << 2);
        v.x = b2f(xp[0]); v.y = b2f(xp[1]); v.z = b2f(xp[2]); v.w = b2f(xp[3]);
    }
    ((float4*)out)[i] = v;
}

// ---------------- bf16 MFMA GEMM: 128x128 tile, BK=64, double-buffered 2-phase ----------------
// EPI 0: h = bf16(gelu(acc+bias))   EPI 1: out[tok] += w*(acc+bias)   EPI 2: atomicAdd variant
template<int GATHER, int EPI, int MERGED>
__global__ __launch_bounds__(256) void moe_gemm_kernel(
    const u16* __restrict__ Abase, const u16* __restrict__ Btbase,
    const float* __restrict__ biasbase,
    const int* __restrict__ sel_tok, const float* __restrict__ sel_w,
    const int* __restrict__ sel_count, int e_arg, int K, int N,
    size_t a_estride, size_t h_estride,
    u16* __restrict__ h_out, float* __restrict__ out)
{
    __shared__ u16 sA[2][128 * 64];
    __shared__ u16 sB[2][128 * 64];

    const int e = MERGED ? blockIdx.z : e_arg;
    const int selc = sel_count[e];
    const int row0 = blockIdx.x * 128;
    if (row0 >= selc) return;
    const int n0 = blockIdx.y * 128;

    const u16* A = Abase + (size_t)e * a_estride;
    const u16* Bt = Btbase + (size_t)e * (size_t)N * K;
    const float* bias = biasbase + (size_t)e * N;
    const int* sel_tok_e = sel_tok + (size_t)e * CAP;
    const float* sel_w_e = sel_w + (size_t)e * CAP;

    const int t = threadIdx.x;
    const int lane = t & 63;
    const int w = t >> 6;
    const int wm = (w >> 1) * 64, wn = (w & 1) * 64;
    const int lr = lane & 15;
    const int lg = lane >> 4;

    const int srow = t >> 3;
    const int sk   = (t & 7) * 8;

    const u16* asrc[4];
    #pragma unroll
    for (int i = 0; i < 4; i++) {
        int r = row0 + i * 32 + srow;
        int gr;
        if (GATHER) gr = (r < selc) ? sel_tok_e[r] : 0;
        else        gr = r;
        asrc[i] = A + (size_t)gr * K + sk;
    }
    const u16* bsrc[4];
    #pragma unroll
    for (int i = 0; i < 4; i++) {
        int nn = n0 + i * 32 + srow;
        bsrc[i] = Bt + (size_t)nn * K + sk;
    }

    f32x4 acc[4][4] = {};
    const int NT = K >> 6;

    // prologue: stage tile 0 into buffer 0
    #pragma unroll
    for (int i = 0; i < 4; i++) gload_lds16(asrc[i], &sA[0][i * 2048 + t * 8]);
    #pragma unroll
    for (int i = 0; i < 4; i++) gload_lds16(bsrc[i], &sB[0][i * 2048 + t * 8]);
    asm volatile("s_waitcnt vmcnt(0)" ::: "memory");
    __builtin_amdgcn_s_barrier();

    int cur = 0;
    for (int kt = 0; kt < NT; ++kt) {
        const int nxt = cur ^ 1;
        if (kt + 1 < NT) {           // issue next-tile loads; they fly during compute
            const int ko = (kt + 1) << 6;
            #pragma unroll
            for (int i = 0; i < 4; i++) gload_lds16(asrc[i] + ko, &sA[nxt][i * 2048 + t * 8]);
            #pragma unroll
            for (int i = 0; i < 4; i++) gload_lds16(bsrc[i] + ko, &sB[nxt][i * 2048 + t * 8]);
        }
        const u16* sAc = &sA[cur][0];
        const u16* sBc = &sB[cur][0];
        #pragma unroll
        for (int kk = 0; kk < 64; kk += 32) {
            short8 af[4], bf[4];
            #pragma unroll
            for (int m = 0; m < 4; m++)
                af[m] = *(const short8*)&sAc[(wm + m * 16 + lr) * 64 + kk + lg * 8];
            #pragma unroll
            for (int n = 0; n < 4; n++)
                bf[n] = *(const short8*)&sBc[(wn + n * 16 + lr) * 64 + kk + lg * 8];
            #pragma unroll
            for (int m = 0; m < 4; m++)
                #pragma unroll
                for (int n = 0; n < 4; n++)
                    acc[m][n] = __builtin_amdgcn_mfma_f32_16x16x32_bf16(af[m], bf[n], acc[m][n], 0, 0, 0);
        }
        asm volatile("s_waitcnt vmcnt(0)" ::: "memory");
        __builtin_amdgcn_s_barrier();
        cur = nxt;
    }

    if (EPI == 0) {
        u16* hO = h_out + (size_t)e * h_estride;
        #pragma unroll
        for (int m = 0; m < 4; m++) {
            int row = row0 + wm + m * 16 + lg * 4;
            #pragma unroll
            for (int n = 0; n < 4; n++) {
                int col = n0 + wn + n * 16 + lr;
                float bb = bias[col];
                #pragma unroll
                for (int r = 0; r < 4; r++) {
                    float vv = acc[m][n][r] + bb;
                    float gel = 0.5f * vv * (1.0f + erff(vv * 0.70710678118654752440f));
                    hO[(size_t)(row + r) * N + col] = f2b(gel);
                }
            }
        }
    } else {
        #pragma unroll
        for (int m = 0; m < 4; m++) {
            int row = row0 + wm + m * 16 + lg * 4;
            #pragma unroll
            for (int r = 0; r < 4; r++) {
                int rr = row + r;
                if (rr < selc) {
                    int tok = sel_tok_e[rr];
                    float wgt = sel_w_e[rr];
                    float* orow = out + (size_t)tok * O_DIM;
                    #pragma unroll
                    for (int n = 0; n < 4; n++) {
                        int col = n0 + wn + n * 16 + lr;
                        float val = wgt * (acc[m][n][r] + bias[col]);
                        if (EPI == 2) atomicAdd(&orow[col], val);
                        else          orow[col] += val;
                    }
                }
            }
        }
    }
}

extern "C" void kernel_launch(void* const* d_in, const int* in_sizes, int n_in,
                              void* d_out, int out_size, void* d_ws, size_t ws_size,
                              hipStream_t stream) {
    const float* x     = (const float*)d_in[0];
    const float* noise = (const float*)d_in[1];
    const float* gamma = (const float*)d_in[2];
    const float* beta  = (const float*)d_in[3];
    const float* Wg    = (const float*)d_in[4];
    const float* bg    = (const float*)d_in[5];
    const float* W1    = (const float*)d_in[6];
    const float* b1    = (const float*)d_in[7];
    const float* W2    = (const float*)d_in[8];
    const float* b2    = (const float*)d_in[9];
    float* out = (float*)d_out;

    char* ws = (char*)d_ws;
    int*    counts    = (int*)(ws + OFF_COUNTS);
    int*    sel_count = (int*)(ws + OFF_SELC);
    int*    bnd_count = (int*)(ws + OFF_BNDC);
    int*    processed = (int*)(ws + OFF_PROC);
    unsigned int* hist = (unsigned int*)(ws + OFF_HIST);
    int*    thr16     = (int*)(ws + OFF_THR);
    int*    rem       = (int*)(ws + OFF_REM);
    float*  cand_w    = (float*)(ws + OFF_CANDW);
    int*    cand_slot = (int*)(ws + OFF_CANDS);
    int*    sel_tok   = (int*)(ws + OFF_SELTOK);
    float*  sel_w     = (float*)(ws + OFF_SELW);
    double* logits    = (double*)(ws + OFF_LOG);
    int*    bnd_slot  = (int*)(ws + OFF_BNDS);
    float*  bnd_w     = (float*)(ws + OFF_BNDW);
    u16*    xnb       = (u16*)(ws + OFF_XNB);
    u16*    W1t       = (u16*)(ws + OFF_W1T);
    u16*    W2t       = (u16*)(ws + OFF_W2T);
    u16*    h         = (u16*)(ws + OFF_H);

    hipMemsetAsync(ws, 0, CTRL_BYTES, stream);
    hipMemsetAsync((char*)d_out + (size_t)T_TOKENS * O_DIM * 4, 0, 4, stream);  // aux_loss = 0

    convert_wt_kernel<<<dim3(H_DIM / 64, D_DIM / 64, E_NUM), 256, 0, stream>>>(W1, W1t, D_DIM, H_DIM);
    convert_wt_kernel<<<dim3(O_DIM / 64, H_DIM / 64, E_NUM), 256, 0, stream>>>(W2, W2t, H_DIM, O_DIM);

    ln_kernel<<<T_TOKENS / 64, 256, 0, stream>>>(x, gamma, beta, Wg, xnb, logits);
    gate_kernel<<<T_TOKENS / 256, 256, 0, stream>>>(logits, noise, bg, counts, cand_w, cand_slot, hist);
    scan_kernel<<<E_NUM, 1024, 0, stream>>>(hist, counts, thr16, rem);
    emit_kernel<<<dim3(64, E_NUM), 256, 0, stream>>>(counts, cand_w, cand_slot, thr16,
                                                     sel_count, sel_tok, sel_w,
                                                     bnd_count, bnd_slot, bnd_w, processed);
    boundary_kernel<<<E_NUM, 256, 0, stream>>>(bnd_count, bnd_slot, bnd_w, rem,
                                               sel_count, sel_tok, sel_w, processed);
    init_out_kernel<<<(T_TOKENS * O_DIM / 4) / 256, 256, 0, stream>>>(xnb, processed, out);

    if (ws_size >= NEED_BIG) {
        // merged: one fc1 dispatch + one fc2 dispatch across all experts
        moe_gemm_kernel<1, 0, 1><<<dim3(CAP / 128, H_DIM / 128, E_NUM), 256, 0, stream>>>(
            xnb, W1t, b1, sel_tok, sel_w, sel_count, 0, D_DIM, H_DIM,
            0, (size_t)CAP * H_DIM, h, nullptr);
        moe_gemm_kernel<0, 2, 1><<<dim3(CAP / 128, O_DIM / 128, E_NUM), 256, 0, stream>>>(
            h, W2t, b2, sel_tok, sel_w, sel_count, 0, H_DIM, O_DIM,
            (size_t)CAP * H_DIM, 0, nullptr, out);
    } else {
        for (int e = 0; e < E_NUM; e++) {
            moe_gemm_kernel<1, 0, 0><<<dim3(CAP / 128, H_DIM / 128), 256, 0, stream>>>(
                xnb, W1t, b1, sel_tok, sel_w, sel_count, e, D_DIM, H_DIM,
                0, 0, h, nullptr);
            moe_gemm_kernel<0, 1, 0><<<dim3(CAP / 128, O_DIM / 128), 256, 0, stream>>>(
                h, W2t, b2, sel_tok, sel_w, sel_count, e, H_DIM, O_DIM,
                0, 0, nullptr, out);
        }
    }
}

// Round 5
// 1051.730 us; speedup vs baseline: 6.8886x; 1.0329x over previous
//
#include <hip/hip_runtime.h>
#include <math.h>

typedef __attribute__((ext_vector_type(4))) float f32x4;
typedef __attribute__((ext_vector_type(8))) short short8;
typedef unsigned short u16;

#define T_TOKENS 65536
#define D_DIM    512
#define H_DIM    2048
#define O_DIM    512
#define E_NUM    8
#define CAP      8192

// ---- workspace layout (bytes) ----
static constexpr size_t OFF_COUNTS = 0;            // 8 ints
static constexpr size_t OFF_SELC   = 64;           // 8 ints
static constexpr size_t OFF_BNDC   = 128;          // 8 ints
static constexpr size_t OFF_PROC   = 192;          // T ints
static constexpr size_t OFF_HIST   = OFF_PROC + (size_t)T_TOKENS * 4;          // E*65536 uints (2MB)
static constexpr size_t CTRL_BYTES = OFF_HIST + (size_t)E_NUM * 65536 * 4;     // zeroed per launch
static constexpr size_t OFF_THR    = CTRL_BYTES;                               // 8 ints
static constexpr size_t OFF_REM    = OFF_THR + 64;                             // 8 ints
static constexpr size_t OFF_CANDW  = OFF_REM + 64;
static constexpr size_t OFF_CANDS  = OFF_CANDW + (size_t)E_NUM * T_TOKENS * 4; // +2MB
static constexpr size_t OFF_SELTOK = OFF_CANDS + (size_t)E_NUM * T_TOKENS * 4; // +2MB
static constexpr size_t OFF_SELW   = OFF_SELTOK + (size_t)E_NUM * CAP * 4;     // +256KB
static constexpr size_t OFF_LOG    = OFF_SELW + (size_t)E_NUM * CAP * 4;       // +256KB, 4MB region
// bnd arrays overlap logits region (logits dead before emit runs)
static constexpr size_t OFF_BNDS   = OFF_LOG;                                  // 1MB
static constexpr size_t OFF_BNDW   = OFF_LOG + (size_t)E_NUM * CAP * 4 * 4;    // 1MB
static constexpr size_t OFF_XNB    = OFF_LOG + (size_t)T_TOKENS * E_NUM * 8;   // +4MB
static constexpr size_t OFF_W1T    = OFF_XNB + (size_t)T_TOKENS * D_DIM * 2;   // +64MB
static constexpr size_t OFF_W2T    = OFF_W1T + (size_t)E_NUM * D_DIM * H_DIM * 2; // +16MB
static constexpr size_t OFF_H      = OFF_W2T + (size_t)E_NUM * H_DIM * O_DIM * 2; // +16MB
static constexpr size_t NEED_SMALL = OFF_H + (size_t)CAP * H_DIM * 2;             // ~139MB
static constexpr size_t NEED_BIG   = OFF_H + (size_t)E_NUM * CAP * H_DIM * 2;     // ~363MB

__device__ __forceinline__ u16 f2b(float f) {            // f32 -> bf16 RNE
    unsigned u = __float_as_uint(f);
    unsigned r = (u + 0x7FFFu + ((u >> 16) & 1u)) >> 16;
    return (u16)r;
}
__device__ __forceinline__ float b2f(u16 b) {
    return __uint_as_float(((unsigned)b) << 16);
}

#define AS1 __attribute__((address_space(1)))
#define AS3 __attribute__((address_space(3)))
__device__ __forceinline__ void gload_lds16(const void* g, void* l) {
    __builtin_amdgcn_global_load_lds((const AS1 void*)g, (AS3 void*)l, 16, 0, 0);
}

// ---------------- LayerNorm + fp64 logits (grid-stride: 64 tokens/block) ----------------
__global__ __launch_bounds__(256) void ln_kernel(
    const float* __restrict__ x, const float* __restrict__ gamma,
    const float* __restrict__ beta, const float* __restrict__ Wg,
    u16* __restrict__ xnb, double* __restrict__ logits)
{
    __shared__ float sWg[E_NUM * D_DIM];
    for (int i = threadIdx.x; i < E_NUM * D_DIM; i += 256) sWg[i] = Wg[i];
    __syncthreads();

    const int wave = threadIdx.x >> 6, lane = threadIdx.x & 63;

    for (int it = 0; it < 16; ++it) {
        const int t = blockIdx.x * 64 + it * 4 + wave;
        const float* xr = x + (size_t)t * D_DIM;

        float xv[8];
        #pragma unroll
        for (int i = 0; i < 8; i++) xv[i] = xr[i * 64 + lane];

        double s = 0.0;
        #pragma unroll
        for (int i = 0; i < 8; i++) s += (double)xv[i];
        #pragma unroll
        for (int o = 32; o > 0; o >>= 1) s += __shfl_xor(s, o);
        double mu = s / 512.0;

        double v = 0.0;
        #pragma unroll
        for (int i = 0; i < 8; i++) { double d = (double)xv[i] - mu; v += d * d; }
        #pragma unroll
        for (int o = 32; o > 0; o >>= 1) v += __shfl_xor(v, o);
        double rstd = 1.0 / sqrt(v / 512.0 + 1e-5);

        float xnf[8];
        #pragma unroll
        for (int i = 0; i < 8; i++) {
            int c = i * 64 + lane;
            double xd = ((double)xv[i] - mu) * rstd * (double)gamma[c] + (double)beta[c];
            xnf[i] = (float)xd;
            xnb[(size_t)t * D_DIM + c] = f2b(xnf[i]);
        }

        double p[E_NUM];
        #pragma unroll
        for (int e = 0; e < E_NUM; e++) p[e] = 0.0;
        #pragma unroll
        for (int i = 0; i < 8; i++) {
            int c = i * 64 + lane;
            double xd = (double)xnf[i];
            #pragma unroll
            for (int e = 0; e < E_NUM; e++) p[e] += xd * (double)sWg[e * D_DIM + c];
        }
        #pragma unroll
        for (int o = 32; o > 0; o >>= 1) {
            #pragma unroll
            for (int e = 0; e < E_NUM; e++) p[e] += __shfl_xor(p[e], o);
        }
        if (lane < 8) {
            double vv = p[0];
            #pragma unroll
            for (int e = 1; e < 8; e++) if (lane == e) vv = p[e];
            logits[(size_t)t * 8 + lane] = vv;
        }
    }
}

// ---------------- gate: softmax + top2 + normalize + 16b-prefix histogram ----------------
__global__ __launch_bounds__(256) void gate_kernel(
    const double* __restrict__ logits, const float* __restrict__ noise,
    const float* __restrict__ bg,
    int* __restrict__ counts, float* __restrict__ cand_w, int* __restrict__ cand_slot,
    unsigned int* __restrict__ hist)
{
    __shared__ int lcnt[E_NUM], lbase[E_NUM];
    if (threadIdx.x < E_NUM) lcnt[threadIdx.x] = 0;
    __syncthreads();
    const int t = blockIdx.x * 256 + threadIdx.x;

    double l[E_NUM], m = -1e300;
    #pragma unroll
    for (int e = 0; e < E_NUM; e++) {
        l[e] = logits[(size_t)t * 8 + e] + (double)bg[e] + 0.125 * (double)noise[(size_t)t * 8 + e];
        if (l[e] > m) m = l[e];
    }
    double sum = 0.0, g[E_NUM];
    #pragma unroll
    for (int e = 0; e < E_NUM; e++) { g[e] = exp(l[e] - m); sum += g[e]; }
    double inv = 1.0 / sum;
    #pragma unroll
    for (int e = 0; e < E_NUM; e++) g[e] *= inv;

    double v1 = -1.0; int i1 = 0;
    #pragma unroll
    for (int e = 0; e < E_NUM; e++) if (g[e] > v1) { v1 = g[e]; i1 = e; }
    double v2 = -1.0; int i2 = 0;
    #pragma unroll
    for (int e = 0; e < E_NUM; e++) if (e != i1 && g[e] > v2) { v2 = g[e]; i2 = e; }

    double denom = v1 + v2 + 1e-20;
    float w1 = (float)(v1 / denom);
    float w2 = (float)(v2 / denom);

    atomicAdd(&hist[(size_t)i1 * 65536 + ((~__float_as_uint(w1)) >> 16)], 1u);
    atomicAdd(&hist[(size_t)i2 * 65536 + ((~__float_as_uint(w2)) >> 16)], 1u);

    int p1 = atomicAdd(&lcnt[i1], 1);
    int p2 = atomicAdd(&lcnt[i2], 1);
    __syncthreads();
    if (threadIdx.x < E_NUM) lbase[threadIdx.x] = atomicAdd(&counts[threadIdx.x], lcnt[threadIdx.x]);
    __syncthreads();
    cand_w[(size_t)i1 * T_TOKENS + lbase[i1] + p1] = w1;
    cand_slot[(size_t)i1 * T_TOKENS + lbase[i1] + p1] = 2 * t;
    cand_w[(size_t)i2 * T_TOKENS + lbase[i2] + p2] = w2;
    cand_slot[(size_t)i2 * T_TOKENS + lbase[i2] + p2] = 2 * t + 1;
}

// ---------------- scan: find 16-bit threshold bin + residual need per expert ----------------
__global__ __launch_bounds__(1024) void scan_kernel(
    const unsigned int* __restrict__ hist, const int* __restrict__ counts,
    int* __restrict__ thr16, int* __restrict__ rem)
{
    const int e = blockIdx.x;
    const int n = counts[e];
    if (n <= CAP) {
        if (threadIdx.x == 0) { thr16[e] = 65536; rem[e] = 0; }
        return;
    }
    const unsigned int* h = hist + (size_t)e * 65536;
    __shared__ unsigned int part[1024];
    const int tid = threadIdx.x;
    unsigned int own = 0;
    const int base = tid * 64;
    #pragma unroll 8
    for (int i = 0; i < 64; i++) own += h[base + i];
    part[tid] = own;
    __syncthreads();
    for (int off = 1; off < 1024; off <<= 1) {
        unsigned int v = (tid >= off) ? part[tid - off] : 0u;
        __syncthreads();
        part[tid] += v;
        __syncthreads();
    }
    unsigned int incl = part[tid];
    unsigned int excl = incl - own;
    const unsigned int need = CAP;
    if (excl < need && incl >= need) {
        unsigned int cum = excl;
        for (int i = 0; i < 64; i++) {
            unsigned int hv = h[base + i];
            if (cum + hv >= need) { thr16[e] = base + i; rem[e] = (int)(need - cum); break; }
            cum += hv;
        }
    }
}

// ---------------- emit: select below-threshold candidates, collect boundary bin ----------------
__global__ __launch_bounds__(256) void emit_kernel(
    const int* __restrict__ counts, const float* __restrict__ cand_w,
    const int* __restrict__ cand_slot, const int* __restrict__ thr16,
    int* __restrict__ sel_count, int* __restrict__ sel_tok, float* __restrict__ sel_w,
    int* __restrict__ bnd_count, int* __restrict__ bnd_slot, float* __restrict__ bnd_w,
    int* __restrict__ processed)
{
    const int e = blockIdx.y;
    const int n = counts[e];
    const int thr = thr16[e];
    const float* cw = cand_w + (size_t)e * T_TOKENS;
    const int* cs = cand_slot + (size_t)e * T_TOKENS;
    for (int i = blockIdx.x * 256 + threadIdx.x; i < n; i += gridDim.x * 256) {
        float w = cw[i];
        int slot = cs[i];
        int p16 = (int)((~__float_as_uint(w)) >> 16);
        if (p16 < thr) {
            int pos = atomicAdd(&sel_count[e], 1);
            sel_tok[e * CAP + pos] = slot >> 1;
            sel_w[e * CAP + pos]  = w;
            processed[slot >> 1] = 1;
        } else if (p16 == thr) {
            int bpos = atomicAdd(&bnd_count[e], 1);
            bnd_slot[(size_t)e * CAP * 4 + bpos] = slot;
            bnd_w[(size_t)e * CAP * 4 + bpos]   = w;
        }
    }
}

// ---------------- boundary: exact rank among boundary-bin candidates ----------------
__global__ __launch_bounds__(256) void boundary_kernel(
    const int* __restrict__ bnd_count, const int* __restrict__ bnd_slot,
    const float* __restrict__ bnd_w, const int* __restrict__ rem,
    int* __restrict__ sel_count, int* __restrict__ sel_tok, float* __restrict__ sel_w,
    int* __restrict__ processed)
{
    const int e = blockIdx.x;
    const int r = rem[e];
    if (r == 0) return;
    const int nb = bnd_count[e];
    const int* bs = bnd_slot + (size_t)e * CAP * 4;
    const float* bw = bnd_w + (size_t)e * CAP * 4;
    for (int i = threadIdx.x; i < nb; i += 256) {
        unsigned long long ki = (((unsigned long long)(~__float_as_uint(bw[i]))) << 32) | (unsigned int)bs[i];
        int rank = 0;
        for (int j = 0; j < nb; j++) {
            unsigned long long kj = (((unsigned long long)(~__float_as_uint(bw[j]))) << 32) | (unsigned int)bs[j];
            rank += (kj < ki);
        }
        if (rank < r) {
            int pos = atomicAdd(&sel_count[e], 1);
            sel_tok[e * CAP + pos] = bs[i] >> 1;
            sel_w[e * CAP + pos]  = bw[i];
            processed[bs[i] >> 1] = 1;
        }
    }
}

// ---------------- W [E][K][N] f32 -> Wt [E][N][K] bf16 (tiled transpose) ----------------
__global__ __launch_bounds__(256) void convert_wt_kernel(
    const float* __restrict__ W, u16* __restrict__ Wt, int K, int N)
{
    __shared__ float tile[64][65];
    const int e = blockIdx.z;
    const int k0 = blockIdx.y * 64, n0 = blockIdx.x * 64;
    const float* We = W + (size_t)e * K * N;
    u16* Wte = Wt + (size_t)e * N * K;
    const int tx = threadIdx.x & 63, ty = threadIdx.x >> 6;
    #pragma unroll
    for (int r = 0; r < 64; r += 4)
        tile[ty + r][tx] = We[(size_t)(k0 + ty + r) * N + n0 + tx];
    __syncthreads();
    #pragma unroll
    for (int r = 0; r < 64; r += 4) {
        int nn = ty + r;
        Wte[(size_t)(n0 + nn) * K + k0 + tx] = f2b(tile[tx][nn]);
    }
}

// ---------------- out = processed ? 0 : xn ----------------
__global__ __launch_bounds__(256) void init_out_kernel(
    const u16* __restrict__ xnb, const int* __restrict__ processed, float* __restrict__ out)
{
    size_t i = (size_t)blockIdx.x * 256 + threadIdx.x;
    int t = (int)(i >> 7);
    float4 v; v.x = 0.f; v.y = 0.f; v.z = 0.f; v.w = 0.f;
    if (!processed[t]) {
        const u16* xp = xnb + (i << 2);
        v.x = b2f(xp[0]); v.y = b2f(xp[1]); v.z = b2f(xp[2]); v.w = b2f(xp[3]);
    }
    ((float4*)out)[i] = v;
}

// ---------------- bf16 MFMA GEMM: 128x128 tile, BK=64, double-buffered, XOR-swizzled LDS ----------------
// Swizzle (T2, rule #21): LDS dest is linear (global_load_lds); global SOURCE k-offset is
// pre-permuted by ((row&7)*8 u16), and the ds_read applies the same XOR. Involution on both
// sides => identical math, but fragment reads hit 8 distinct 16B slots instead of 1.
// EPI 0: h = bf16(gelu(acc+bias))   EPI 1: out[tok] += w*(acc+bias)   EPI 2: atomicAdd variant
template<int GATHER, int EPI, int MERGED>
__global__ __launch_bounds__(256) void moe_gemm_kernel(
    const u16* __restrict__ Abase, const u16* __restrict__ Btbase,
    const float* __restrict__ biasbase,
    const int* __restrict__ sel_tok, const float* __restrict__ sel_w,
    const int* __restrict__ sel_count, int e_arg, int K, int N,
    size_t a_estride, size_t h_estride,
    u16* __restrict__ h_out, float* __restrict__ out)
{
    __shared__ u16 sA[2][128 * 64];
    __shared__ u16 sB[2][128 * 64];

    const int e = MERGED ? blockIdx.z : e_arg;
    const int selc = sel_count[e];
    const int row0 = blockIdx.x * 128;
    if (row0 >= selc) return;
    const int n0 = blockIdx.y * 128;

    const u16* A = Abase + (size_t)e * a_estride;
    const u16* Bt = Btbase + (size_t)e * (size_t)N * K;
    const float* bias = biasbase + (size_t)e * N;
    const int* sel_tok_e = sel_tok + (size_t)e * CAP;
    const float* sel_w_e = sel_w + (size_t)e * CAP;

    const int t = threadIdx.x;
    const int lane = t & 63;
    const int w = t >> 6;
    const int wm = (w >> 1) * 64, wn = (w & 1) * 64;
    const int lr = lane & 15;
    const int lg = lane >> 4;

    const int srow = t >> 3;                               // 0..31 : row within 32-row staging group
    const int sk   = (((t & 7) ^ (srow & 7)) * 8);         // pre-swizzled source k-offset (u16)

    const u16* asrc[4];
    #pragma unroll
    for (int i = 0; i < 4; i++) {
        int r = row0 + i * 32 + srow;
        int gr;
        if (GATHER) gr = (r < selc) ? sel_tok_e[r] : 0;
        else        gr = r;
        asrc[i] = A + (size_t)gr * K + sk;
    }
    const u16* bsrc[4];
    #pragma unroll
    for (int i = 0; i < 4; i++) {
        int nn = n0 + i * 32 + srow;
        bsrc[i] = Bt + (size_t)nn * K + sk;
    }

    f32x4 acc[4][4] = {};
    const int NT = K >> 6;

    // prologue: stage tile 0 into buffer 0
    #pragma unroll
    for (int i = 0; i < 4; i++) gload_lds16(asrc[i], &sA[0][i * 2048 + t * 8]);
    #pragma unroll
    for (int i = 0; i < 4; i++) gload_lds16(bsrc[i], &sB[0][i * 2048 + t * 8]);
    asm volatile("s_waitcnt vmcnt(0)" ::: "memory");
    __builtin_amdgcn_s_barrier();

    int cur = 0;
    for (int kt = 0; kt < NT; ++kt) {
        const int nxt = cur ^ 1;
        if (kt + 1 < NT) {           // issue next-tile loads; they fly during compute
            const int ko = (kt + 1) << 6;
            #pragma unroll
            for (int i = 0; i < 4; i++) gload_lds16(asrc[i] + ko, &sA[nxt][i * 2048 + t * 8]);
            #pragma unroll
            for (int i = 0; i < 4; i++) gload_lds16(bsrc[i] + ko, &sB[nxt][i * 2048 + t * 8]);
        }
        const u16* sAc = &sA[cur][0];
        const u16* sBc = &sB[cur][0];
        #pragma unroll
        for (int kk = 0; kk < 64; kk += 32) {
            short8 af[4], bf[4];
            #pragma unroll
            for (int m = 0; m < 4; m++) {
                int ar = wm + m * 16 + lr;
                af[m] = *(const short8*)&sAc[ar * 64 + ((kk + lg * 8) ^ ((ar & 7) * 8))];
            }
            #pragma unroll
            for (int n = 0; n < 4; n++) {
                int br = wn + n * 16 + lr;
                bf[n] = *(const short8*)&sBc[br * 64 + ((kk + lg * 8) ^ ((br & 7) * 8))];
            }
            #pragma unroll
            for (int m = 0; m < 4; m++)
                #pragma unroll
                for (int n = 0; n < 4; n++)
                    acc[m][n] = __builtin_amdgcn_mfma_f32_16x16x32_bf16(af[m], bf[n], acc[m][n], 0, 0, 0);
        }
        asm volatile("s_waitcnt vmcnt(0)" ::: "memory");
        __builtin_amdgcn_s_barrier();
        cur = nxt;
    }

    if (EPI == 0) {
        u16* hO = h_out + (size_t)e * h_estride;
        #pragma unroll
        for (int m = 0; m < 4; m++) {
            int row = row0 + wm + m * 16 + lg * 4;
            #pragma unroll
            for (int n = 0; n < 4; n++) {
                int col = n0 + wn + n * 16 + lr;
                float bb = bias[col];
                #pragma unroll
                for (int r = 0; r < 4; r++) {
                    float vv = acc[m][n][r] + bb;
                    float gel = 0.5f * vv * (1.0f + erff(vv * 0.70710678118654752440f));
                    hO[(size_t)(row + r) * N + col] = f2b(gel);
                }
            }
        }
    } else {
        #pragma unroll
        for (int m = 0; m < 4; m++) {
            int row = row0 + wm + m * 16 + lg * 4;
            #pragma unroll
            for (int r = 0; r < 4; r++) {
                int rr = row + r;
                if (rr < selc) {
                    int tok = sel_tok_e[rr];
                    float wgt = sel_w_e[rr];
                    float* orow = out + (size_t)tok * O_DIM;
                    #pragma unroll
                    for (int n = 0; n < 4; n++) {
                        int col = n0 + wn + n * 16 + lr;
                        float val = wgt * (acc[m][n][r] + bias[col]);
                        if (EPI == 2) atomicAdd(&orow[col], val);
                        else          orow[col] += val;
                    }
                }
            }
        }
    }
}

extern "C" void kernel_launch(void* const* d_in, const int* in_sizes, int n_in,
                              void* d_out, int out_size, void* d_ws, size_t ws_size,
                              hipStream_t stream) {
    const float* x     = (const float*)d_in[0];
    const float* noise = (const float*)d_in[1];
    const float* gamma = (const float*)d_in[2];
    const float* beta  = (const float*)d_in[3];
    const float* Wg    = (const float*)d_in[4];
    const float* bg    = (const float*)d_in[5];
    const float* W1    = (const float*)d_in[6];
    const float* b1    = (const float*)d_in[7];
    const float* W2    = (const float*)d_in[8];
    const float* b2    = (const float*)d_in[9];
    float* out = (float*)d_out;

    char* ws = (char*)d_ws;
    int*    counts    = (int*)(ws + OFF_COUNTS);
    int*    sel_count = (int*)(ws + OFF_SELC);
    int*    bnd_count = (int*)(ws + OFF_BNDC);
    int*    processed = (int*)(ws + OFF_PROC);
    unsigned int* hist = (unsigned int*)(ws + OFF_HIST);
    int*    thr16     = (int*)(ws + OFF_THR);
    int*    rem       = (int*)(ws + OFF_REM);
    float*  cand_w    = (float*)(ws + OFF_CANDW);
    int*    cand_slot = (int*)(ws + OFF_CANDS);
    int*    sel_tok   = (int*)(ws + OFF_SELTOK);
    float*  sel_w     = (float*)(ws + OFF_SELW);
    double* logits    = (double*)(ws + OFF_LOG);
    int*    bnd_slot  = (int*)(ws + OFF_BNDS);
    float*  bnd_w     = (float*)(ws + OFF_BNDW);
    u16*    xnb       = (u16*)(ws + OFF_XNB);
    u16*    W1t       = (u16*)(ws + OFF_W1T);
    u16*    W2t       = (u16*)(ws + OFF_W2T);
    u16*    h         = (u16*)(ws + OFF_H);

    hipMemsetAsync(ws, 0, CTRL_BYTES, stream);
    hipMemsetAsync((char*)d_out + (size_t)T_TOKENS * O_DIM * 4, 0, 4, stream);  // aux_loss = 0

    convert_wt_kernel<<<dim3(H_DIM / 64, D_DIM / 64, E_NUM), 256, 0, stream>>>(W1, W1t, D_DIM, H_DIM);
    convert_wt_kernel<<<dim3(O_DIM / 64, H_DIM / 64, E_NUM), 256, 0, stream>>>(W2, W2t, H_DIM, O_DIM);

    ln_kernel<<<T_TOKENS / 64, 256, 0, stream>>>(x, gamma, beta, Wg, xnb, logits);
    gate_kernel<<<T_TOKENS / 256, 256, 0, stream>>>(logits, noise, bg, counts, cand_w, cand_slot, hist);
    scan_kernel<<<E_NUM, 1024, 0, stream>>>(hist, counts, thr16, rem);
    emit_kernel<<<dim3(64, E_NUM), 256, 0, stream>>>(counts, cand_w, cand_slot, thr16,
                                                     sel_count, sel_tok, sel_w,
                                                     bnd_count, bnd_slot, bnd_w, processed);
    boundary_kernel<<<E_NUM, 256, 0, stream>>>(bnd_count, bnd_slot, bnd_w, rem,
                                               sel_count, sel_tok, sel_w, processed);
    init_out_kernel<<<(T_TOKENS * O_DIM / 4) / 256, 256, 0, stream>>>(xnb, processed, out);

    if (ws_size >= NEED_BIG) {
        // merged: one fc1 dispatch + one fc2 dispatch across all experts
        moe_gemm_kernel<1, 0, 1><<<dim3(CAP / 128, H_DIM / 128, E_NUM), 256, 0, stream>>>(
            xnb, W1t, b1, sel_tok, sel_w, sel_count, 0, D_DIM, H_DIM,
            0, (size_t)CAP * H_DIM, h, nullptr);
        moe_gemm_kernel<0, 2, 1><<<dim3(CAP / 128, O_DIM / 128, E_NUM), 256, 0, stream>>>(
            h, W2t, b2, sel_tok, sel_w, sel_count, 0, H_DIM, O_DIM,
            (size_t)CAP * H_DIM, 0, nullptr, out);
    } else {
        for (int e = 0; e < E_NUM; e++) {
            moe_gemm_kernel<1, 0, 0><<<dim3(CAP / 128, H_DIM / 128), 256, 0, stream>>>(
                xnb, W1t, b1, sel_tok, sel_w, sel_count, e, D_DIM, H_DIM,
                0, 0, h, nullptr);
            moe_gemm_kernel<0, 1, 0><<<dim3(CAP / 128, O_DIM / 128), 256, 0, stream>>>(
                h, W2t, b2, sel_tok, sel_w, sel_count, e, H_DIM, O_DIM,
                0, 0, nullptr, out);
        }
    }
}

// Round 6
// 1004.353 us; speedup vs baseline: 7.2135x; 1.0472x over previous
//
#include <hip/hip_runtime.h>
#include <math.h>

typedef __attribute__((ext_vector_type(4))) float f32x4;
typedef __attribute__((ext_vector_type(8))) short short8;
typedef unsigned short u16;

#define T_TOKENS 65536
#define D_DIM    512
#define H_DIM    2048
#define O_DIM    512
#define E_NUM    8
#define CAP      8192

// ---- workspace layout (bytes) ----
static constexpr size_t OFF_COUNTS = 0;            // 8 ints
static constexpr size_t OFF_SELC   = 64;           // 8 ints
static constexpr size_t OFF_BNDC   = 128;          // 8 ints
static constexpr size_t OFF_PROC   = 192;          // T ints
static constexpr size_t OFF_HIST   = OFF_PROC + (size_t)T_TOKENS * 4;          // E*65536 uints (2MB)
static constexpr size_t CTRL_BYTES = OFF_HIST + (size_t)E_NUM * 65536 * 4;     // zeroed per launch
static constexpr size_t OFF_THR    = CTRL_BYTES;                               // 8 ints
static constexpr size_t OFF_REM    = OFF_THR + 64;                             // 8 ints
static constexpr size_t OFF_CANDW  = OFF_REM + 64;
static constexpr size_t OFF_CANDS  = OFF_CANDW + (size_t)E_NUM * T_TOKENS * 4; // +2MB
static constexpr size_t OFF_SELTOK = OFF_CANDS + (size_t)E_NUM * T_TOKENS * 4; // +2MB
static constexpr size_t OFF_SELW   = OFF_SELTOK + (size_t)E_NUM * CAP * 4;     // +256KB
static constexpr size_t OFF_LOG    = OFF_SELW + (size_t)E_NUM * CAP * 4;       // +256KB, 4MB region
// bnd arrays overlap logits region (logits dead before emit runs)
static constexpr size_t OFF_BNDS   = OFF_LOG;                                  // 1MB
static constexpr size_t OFF_BNDW   = OFF_LOG + (size_t)E_NUM * CAP * 4 * 4;    // 1MB
static constexpr size_t OFF_XNB    = OFF_LOG + (size_t)T_TOKENS * E_NUM * 8;   // +4MB
static constexpr size_t OFF_W1T    = OFF_XNB + (size_t)T_TOKENS * D_DIM * 2;   // +64MB
static constexpr size_t OFF_W2T    = OFF_W1T + (size_t)E_NUM * D_DIM * H_DIM * 2; // +16MB
static constexpr size_t OFF_H      = OFF_W2T + (size_t)E_NUM * H_DIM * O_DIM * 2; // +16MB
static constexpr size_t NEED_SMALL = OFF_H + (size_t)CAP * H_DIM * 2;             // ~139MB
static constexpr size_t NEED_BIG   = OFF_H + (size_t)E_NUM * CAP * H_DIM * 2;     // ~363MB

__device__ __forceinline__ u16 f2b(float f) {            // f32 -> bf16 RNE
    unsigned u = __float_as_uint(f);
    unsigned r = (u + 0x7FFFu + ((u >> 16) & 1u)) >> 16;
    return (u16)r;
}
__device__ __forceinline__ float b2f(u16 b) {
    return __uint_as_float(((unsigned)b) << 16);
}

#define AS1 __attribute__((address_space(1)))
#define AS3 __attribute__((address_space(3)))
__device__ __forceinline__ void gload_lds16(const void* g, void* l) {
    __builtin_amdgcn_global_load_lds((const AS1 void*)g, (AS3 void*)l, 16, 0, 0);
}

// ---------------- LayerNorm + fp64 logits (grid-stride: 64 tokens/block) ----------------
__global__ __launch_bounds__(256) void ln_kernel(
    const float* __restrict__ x, const float* __restrict__ gamma,
    const float* __restrict__ beta, const float* __restrict__ Wg,
    u16* __restrict__ xnb, double* __restrict__ logits)
{
    __shared__ float sWg[E_NUM * D_DIM];
    for (int i = threadIdx.x; i < E_NUM * D_DIM; i += 256) sWg[i] = Wg[i];
    __syncthreads();

    const int wave = threadIdx.x >> 6, lane = threadIdx.x & 63;

    for (int it = 0; it < 16; ++it) {
        const int t = blockIdx.x * 64 + it * 4 + wave;
        const float* xr = x + (size_t)t * D_DIM;

        float xv[8];
        #pragma unroll
        for (int i = 0; i < 8; i++) xv[i] = xr[i * 64 + lane];

        double s = 0.0;
        #pragma unroll
        for (int i = 0; i < 8; i++) s += (double)xv[i];
        #pragma unroll
        for (int o = 32; o > 0; o >>= 1) s += __shfl_xor(s, o);
        double mu = s / 512.0;

        double v = 0.0;
        #pragma unroll
        for (int i = 0; i < 8; i++) { double d = (double)xv[i] - mu; v += d * d; }
        #pragma unroll
        for (int o = 32; o > 0; o >>= 1) v += __shfl_xor(v, o);
        double rstd = 1.0 / sqrt(v / 512.0 + 1e-5);

        float xnf[8];
        #pragma unroll
        for (int i = 0; i < 8; i++) {
            int c = i * 64 + lane;
            double xd = ((double)xv[i] - mu) * rstd * (double)gamma[c] + (double)beta[c];
            xnf[i] = (float)xd;
            xnb[(size_t)t * D_DIM + c] = f2b(xnf[i]);
        }

        double p[E_NUM];
        #pragma unroll
        for (int e = 0; e < E_NUM; e++) p[e] = 0.0;
        #pragma unroll
        for (int i = 0; i < 8; i++) {
            int c = i * 64 + lane;
            double xd = (double)xnf[i];
            #pragma unroll
            for (int e = 0; e < E_NUM; e++) p[e] += xd * (double)sWg[e * D_DIM + c];
        }
        #pragma unroll
        for (int o = 32; o > 0; o >>= 1) {
            #pragma unroll
            for (int e = 0; e < E_NUM; e++) p[e] += __shfl_xor(p[e], o);
        }
        if (lane < 8) {
            double vv = p[0];
            #pragma unroll
            for (int e = 1; e < 8; e++) if (lane == e) vv = p[e];
            logits[(size_t)t * 8 + lane] = vv;
        }
    }
}

// ---------------- gate: softmax + top2 + normalize + 16b-prefix histogram ----------------
__global__ __launch_bounds__(256) void gate_kernel(
    const double* __restrict__ logits, const float* __restrict__ noise,
    const float* __restrict__ bg,
    int* __restrict__ counts, float* __restrict__ cand_w, int* __restrict__ cand_slot,
    unsigned int* __restrict__ hist)
{
    __shared__ int lcnt[E_NUM], lbase[E_NUM];
    if (threadIdx.x < E_NUM) lcnt[threadIdx.x] = 0;
    __syncthreads();
    const int t = blockIdx.x * 256 + threadIdx.x;

    double l[E_NUM], m = -1e300;
    #pragma unroll
    for (int e = 0; e < E_NUM; e++) {
        l[e] = logits[(size_t)t * 8 + e] + (double)bg[e] + 0.125 * (double)noise[(size_t)t * 8 + e];
        if (l[e] > m) m = l[e];
    }
    double sum = 0.0, g[E_NUM];
    #pragma unroll
    for (int e = 0; e < E_NUM; e++) { g[e] = exp(l[e] - m); sum += g[e]; }
    double inv = 1.0 / sum;
    #pragma unroll
    for (int e = 0; e < E_NUM; e++) g[e] *= inv;

    double v1 = -1.0; int i1 = 0;
    #pragma unroll
    for (int e = 0; e < E_NUM; e++) if (g[e] > v1) { v1 = g[e]; i1 = e; }
    double v2 = -1.0; int i2 = 0;
    #pragma unroll
    for (int e = 0; e < E_NUM; e++) if (e != i1 && g[e] > v2) { v2 = g[e]; i2 = e; }

    double denom = v1 + v2 + 1e-20;
    float w1 = (float)(v1 / denom);
    float w2 = (float)(v2 / denom);

    atomicAdd(&hist[(size_t)i1 * 65536 + ((~__float_as_uint(w1)) >> 16)], 1u);
    atomicAdd(&hist[(size_t)i2 * 65536 + ((~__float_as_uint(w2)) >> 16)], 1u);

    int p1 = atomicAdd(&lcnt[i1], 1);
    int p2 = atomicAdd(&lcnt[i2], 1);
    __syncthreads();
    if (threadIdx.x < E_NUM) lbase[threadIdx.x] = atomicAdd(&counts[threadIdx.x], lcnt[threadIdx.x]);
    __syncthreads();
    cand_w[(size_t)i1 * T_TOKENS + lbase[i1] + p1] = w1;
    cand_slot[(size_t)i1 * T_TOKENS + lbase[i1] + p1] = 2 * t;
    cand_w[(size_t)i2 * T_TOKENS + lbase[i2] + p2] = w2;
    cand_slot[(size_t)i2 * T_TOKENS + lbase[i2] + p2] = 2 * t + 1;
}

// ---------------- scan: find 16-bit threshold bin + residual need per expert ----------------
__global__ __launch_bounds__(1024) void scan_kernel(
    const unsigned int* __restrict__ hist, const int* __restrict__ counts,
    int* __restrict__ thr16, int* __restrict__ rem)
{
    const int e = blockIdx.x;
    const int n = counts[e];
    if (n <= CAP) {
        if (threadIdx.x == 0) { thr16[e] = 65536; rem[e] = 0; }
        return;
    }
    const unsigned int* h = hist + (size_t)e * 65536;
    __shared__ unsigned int part[1024];
    const int tid = threadIdx.x;
    unsigned int own = 0;
    const int base = tid * 64;
    #pragma unroll 8
    for (int i = 0; i < 64; i++) own += h[base + i];
    part[tid] = own;
    __syncthreads();
    for (int off = 1; off < 1024; off <<= 1) {
        unsigned int v = (tid >= off) ? part[tid - off] : 0u;
        __syncthreads();
        part[tid] += v;
        __syncthreads();
    }
    unsigned int incl = part[tid];
    unsigned int excl = incl - own;
    const unsigned int need = CAP;
    if (excl < need && incl >= need) {
        unsigned int cum = excl;
        for (int i = 0; i < 64; i++) {
            unsigned int hv = h[base + i];
            if (cum + hv >= need) { thr16[e] = base + i; rem[e] = (int)(need - cum); break; }
            cum += hv;
        }
    }
}

// ---------------- emit: select below-threshold candidates, collect boundary bin ----------------
__global__ __launch_bounds__(256) void emit_kernel(
    const int* __restrict__ counts, const float* __restrict__ cand_w,
    const int* __restrict__ cand_slot, const int* __restrict__ thr16,
    int* __restrict__ sel_count, int* __restrict__ sel_tok, float* __restrict__ sel_w,
    int* __restrict__ bnd_count, int* __restrict__ bnd_slot, float* __restrict__ bnd_w,
    int* __restrict__ processed)
{
    const int e = blockIdx.y;
    const int n = counts[e];
    const int thr = thr16[e];
    const float* cw = cand_w + (size_t)e * T_TOKENS;
    const int* cs = cand_slot + (size_t)e * T_TOKENS;
    for (int i = blockIdx.x * 256 + threadIdx.x; i < n; i += gridDim.x * 256) {
        float w = cw[i];
        int slot = cs[i];
        int p16 = (int)((~__float_as_uint(w)) >> 16);
        if (p16 < thr) {
            int pos = atomicAdd(&sel_count[e], 1);
            sel_tok[e * CAP + pos] = slot >> 1;
            sel_w[e * CAP + pos]  = w;
            processed[slot >> 1] = 1;
        } else if (p16 == thr) {
            int bpos = atomicAdd(&bnd_count[e], 1);
            bnd_slot[(size_t)e * CAP * 4 + bpos] = slot;
            bnd_w[(size_t)e * CAP * 4 + bpos]   = w;
        }
    }
}

// ---------------- boundary: exact rank among boundary-bin candidates ----------------
__global__ __launch_bounds__(256) void boundary_kernel(
    const int* __restrict__ bnd_count, const int* __restrict__ bnd_slot,
    const float* __restrict__ bnd_w, const int* __restrict__ rem,
    int* __restrict__ sel_count, int* __restrict__ sel_tok, float* __restrict__ sel_w,
    int* __restrict__ processed)
{
    const int e = blockIdx.x;
    const int r = rem[e];
    if (r == 0) return;
    const int nb = bnd_count[e];
    const int* bs = bnd_slot + (size_t)e * CAP * 4;
    const float* bw = bnd_w + (size_t)e * CAP * 4;
    for (int i = threadIdx.x; i < nb; i += 256) {
        unsigned long long ki = (((unsigned long long)(~__float_as_uint(bw[i]))) << 32) | (unsigned int)bs[i];
        int rank = 0;
        for (int j = 0; j < nb; j++) {
            unsigned long long kj = (((unsigned long long)(~__float_as_uint(bw[j]))) << 32) | (unsigned int)bs[j];
            rank += (kj < ki);
        }
        if (rank < r) {
            int pos = atomicAdd(&sel_count[e], 1);
            sel_tok[e * CAP + pos] = bs[i] >> 1;
            sel_w[e * CAP + pos]  = bw[i];
            processed[bs[i] >> 1] = 1;
        }
    }
}

// ---------------- W [E][K][N] f32 -> Wt [E][N][K] bf16 (tiled transpose) ----------------
__global__ __launch_bounds__(256) void convert_wt_kernel(
    const float* __restrict__ W, u16* __restrict__ Wt, int K, int N)
{
    __shared__ float tile[64][65];
    const int e = blockIdx.z;
    const int k0 = blockIdx.y * 64, n0 = blockIdx.x * 64;
    const float* We = W + (size_t)e * K * N;
    u16* Wte = Wt + (size_t)e * N * K;
    const int tx = threadIdx.x & 63, ty = threadIdx.x >> 6;
    #pragma unroll
    for (int r = 0; r < 64; r += 4)
        tile[ty + r][tx] = We[(size_t)(k0 + ty + r) * N + n0 + tx];
    __syncthreads();
    #pragma unroll
    for (int r = 0; r < 64; r += 4) {
        int nn = ty + r;
        Wte[(size_t)(n0 + nn) * K + k0 + tx] = f2b(tile[tx][nn]);
    }
}

// ---------------- out = processed ? 0 : xn ----------------
__global__ __launch_bounds__(256) void init_out_kernel(
    const u16* __restrict__ xnb, const int* __restrict__ processed, float* __restrict__ out)
{
    size_t i = (size_t)blockIdx.x * 256 + threadIdx.x;
    int t = (int)(i >> 7);
    float4 v; v.x = 0.f; v.y = 0.f; v.z = 0.f; v.w = 0.f;
    if (!processed[t]) {
        const u16* xp = xnb + (i << 2);
        v.x = b2f(xp[0]); v.y = b2f(xp[1]); v.z = b2f(xp[2]); v.w = b2f(xp[3]);
    }
    ((float4*)out)[i] = v;
}

// ---------------- bf16 MFMA GEMM: 256x256 tile, BK=64, 8 waves (2Mx4N), dbuf, XOR-swizzled LDS ----------
// Per-wave output 128x64 (8x4 frags of 16x16x32). LDS 128KiB (2 x (32KB A + 32KB B)).
// Swizzle (T2, rule #21): LDS dest linear (global_load_lds), global SOURCE k-offset pre-permuted
// by ((row&7)*8 u16); ds_read applies the same XOR. Involution both sides => identical math.
// EPI 0: h = bf16(gelu(acc+bias))   EPI 1: out[tok] += w*(acc+bias)   EPI 2: atomicAdd variant
template<int GATHER, int EPI, int MERGED>
__global__ __launch_bounds__(512) void moe_gemm_kernel(
    const u16* __restrict__ Abase, const u16* __restrict__ Btbase,
    const float* __restrict__ biasbase,
    const int* __restrict__ sel_tok, const float* __restrict__ sel_w,
    const int* __restrict__ sel_count, int e_arg, int K, int N,
    size_t a_estride, size_t h_estride,
    u16* __restrict__ h_out, float* __restrict__ out)
{
    __shared__ u16 sA[2][256 * 64];   // 32KB each buf
    __shared__ u16 sB[2][256 * 64];   // 32KB each buf

    const int e = MERGED ? blockIdx.z : e_arg;
    const int selc = sel_count[e];
    const int row0 = blockIdx.x * 256;
    if (row0 >= selc) return;
    const int n0 = blockIdx.y * 256;

    const u16* A = Abase + (size_t)e * a_estride;
    const u16* Bt = Btbase + (size_t)e * (size_t)N * K;
    const float* bias = biasbase + (size_t)e * N;
    const int* sel_tok_e = sel_tok + (size_t)e * CAP;
    const float* sel_w_e = sel_w + (size_t)e * CAP;

    const int t = threadIdx.x;            // 0..511
    const int lane = t & 63;
    const int w = t >> 6;                 // 0..7
    const int wm = (w >> 2) * 128;        // wave M base (2 row groups)
    const int wn = (w & 3) * 64;          // wave N base (4 col groups)
    const int lr = lane & 15;
    const int lg = lane >> 4;

    const int srow = t >> 3;                               // 0..63 : row within 64-row staging group
    const int sk   = (((t & 7) ^ (srow & 7)) * 8);         // pre-swizzled source k-offset (u16)

    const u16* asrc[4];
    #pragma unroll
    for (int i = 0; i < 4; i++) {
        int r = row0 + i * 64 + srow;
        int gr;
        if (GATHER) gr = (r < selc) ? sel_tok_e[r] : 0;
        else        gr = r;
        asrc[i] = A + (size_t)gr * K + sk;
    }
    const u16* bsrc[4];
    #pragma unroll
    for (int i = 0; i < 4; i++) {
        int nn = n0 + i * 64 + srow;
        bsrc[i] = Bt + (size_t)nn * K + sk;
    }

    f32x4 acc[8][4] = {};
    const int NT = K >> 6;

    // prologue: stage tile 0 into buffer 0 (each inst: 64 rows x 64 k = 8KB; 512 thr x 16B)
    #pragma unroll
    for (int i = 0; i < 4; i++) gload_lds16(asrc[i], &sA[0][i * 4096 + t * 8]);
    #pragma unroll
    for (int i = 0; i < 4; i++) gload_lds16(bsrc[i], &sB[0][i * 4096 + t * 8]);
    asm volatile("s_waitcnt vmcnt(0)" ::: "memory");
    __builtin_amdgcn_s_barrier();

    int cur = 0;
    for (int kt = 0; kt < NT; ++kt) {
        const int nxt = cur ^ 1;
        if (kt + 1 < NT) {           // issue next-tile loads; they fly during compute
            const int ko = (kt + 1) << 6;
            #pragma unroll
            for (int i = 0; i < 4; i++) gload_lds16(asrc[i] + ko, &sA[nxt][i * 4096 + t * 8]);
            #pragma unroll
            for (int i = 0; i < 4; i++) gload_lds16(bsrc[i] + ko, &sB[nxt][i * 4096 + t * 8]);
        }
        const u16* sAc = &sA[cur][0];
        const u16* sBc = &sB[cur][0];
        #pragma unroll
        for (int kk = 0; kk < 64; kk += 32) {
            short8 af[8], bf[4];
            #pragma unroll
            for (int m = 0; m < 8; m++) {
                int ar = wm + m * 16 + lr;
                af[m] = *(const short8*)&sAc[ar * 64 + ((kk + lg * 8) ^ ((ar & 7) * 8))];
            }
            #pragma unroll
            for (int n = 0; n < 4; n++) {
                int br = wn + n * 16 + lr;
                bf[n] = *(const short8*)&sBc[br * 64 + ((kk + lg * 8) ^ ((br & 7) * 8))];
            }
            #pragma unroll
            for (int m = 0; m < 8; m++)
                #pragma unroll
                for (int n = 0; n < 4; n++)
                    acc[m][n] = __builtin_amdgcn_mfma_f32_16x16x32_bf16(af[m], bf[n], acc[m][n], 0, 0, 0);
        }
        asm volatile("s_waitcnt vmcnt(0)" ::: "memory");
        __builtin_amdgcn_s_barrier();
        cur = nxt;
    }

    if (EPI == 0) {
        u16* hO = h_out + (size_t)e * h_estride;
        #pragma unroll
        for (int m = 0; m < 8; m++) {
            int row = row0 + wm + m * 16 + lg * 4;
            #pragma unroll
            for (int n = 0; n < 4; n++) {
                int col = n0 + wn + n * 16 + lr;
                float bb = bias[col];
                #pragma unroll
                for (int r = 0; r < 4; r++) {
                    float vv = acc[m][n][r] + bb;
                    float gel = 0.5f * vv * (1.0f + erff(vv * 0.70710678118654752440f));
                    hO[(size_t)(row + r) * N + col] = f2b(gel);
                }
            }
        }
    } else {
        #pragma unroll
        for (int m = 0; m < 8; m++) {
            int row = row0 + wm + m * 16 + lg * 4;
            #pragma unroll
            for (int r = 0; r < 4; r++) {
                int rr = row + r;
                if (rr < selc) {
                    int tok = sel_tok_e[rr];
                    float wgt = sel_w_e[rr];
                    float* orow = out + (size_t)tok * O_DIM;
                    #pragma unroll
                    for (int n = 0; n < 4; n++) {
                        int col = n0 + wn + n * 16 + lr;
                        float val = wgt * (acc[m][n][r] + bias[col]);
                        if (EPI == 2) atomicAdd(&orow[col], val);
                        else          orow[col] += val;
                    }
                }
            }
        }
    }
}

extern "C" void kernel_launch(void* const* d_in, const int* in_sizes, int n_in,
                              void* d_out, int out_size, void* d_ws, size_t ws_size,
                              hipStream_t stream) {
    const float* x     = (const float*)d_in[0];
    const float* noise = (const float*)d_in[1];
    const float* gamma = (const float*)d_in[2];
    const float* beta  = (const float*)d_in[3];
    const float* Wg    = (const float*)d_in[4];
    const float* bg    = (const float*)d_in[5];
    const float* W1    = (const float*)d_in[6];
    const float* b1    = (const float*)d_in[7];
    const float* W2    = (const float*)d_in[8];
    const float* b2    = (const float*)d_in[9];
    float* out = (float*)d_out;

    char* ws = (char*)d_ws;
    int*    counts    = (int*)(ws + OFF_COUNTS);
    int*    sel_count = (int*)(ws + OFF_SELC);
    int*    bnd_count = (int*)(ws + OFF_BNDC);
    int*    processed = (int*)(ws + OFF_PROC);
    unsigned int* hist = (unsigned int*)(ws + OFF_HIST);
    int*    thr16     = (int*)(ws + OFF_THR);
    int*    rem       = (int*)(ws + OFF_REM);
    float*  cand_w    = (float*)(ws + OFF_CANDW);
    int*    cand_slot = (int*)(ws + OFF_CANDS);
    int*    sel_tok   = (int*)(ws + OFF_SELTOK);
    float*  sel_w     = (float*)(ws + OFF_SELW);
    double* logits    = (double*)(ws + OFF_LOG);
    int*    bnd_slot  = (int*)(ws + OFF_BNDS);
    float*  bnd_w     = (float*)(ws + OFF_BNDW);
    u16*    xnb       = (u16*)(ws + OFF_XNB);
    u16*    W1t       = (u16*)(ws + OFF_W1T);
    u16*    W2t       = (u16*)(ws + OFF_W2T);
    u16*    h         = (u16*)(ws + OFF_H);

    hipMemsetAsync(ws, 0, CTRL_BYTES, stream);
    hipMemsetAsync((char*)d_out + (size_t)T_TOKENS * O_DIM * 4, 0, 4, stream);  // aux_loss = 0

    convert_wt_kernel<<<dim3(H_DIM / 64, D_DIM / 64, E_NUM), 256, 0, stream>>>(W1, W1t, D_DIM, H_DIM);
    convert_wt_kernel<<<dim3(O_DIM / 64, H_DIM / 64, E_NUM), 256, 0, stream>>>(W2, W2t, H_DIM, O_DIM);

    ln_kernel<<<T_TOKENS / 64, 256, 0, stream>>>(x, gamma, beta, Wg, xnb, logits);
    gate_kernel<<<T_TOKENS / 256, 256, 0, stream>>>(logits, noise, bg, counts, cand_w, cand_slot, hist);
    scan_kernel<<<E_NUM, 1024, 0, stream>>>(hist, counts, thr16, rem);
    emit_kernel<<<dim3(64, E_NUM), 256, 0, stream>>>(counts, cand_w, cand_slot, thr16,
                                                     sel_count, sel_tok, sel_w,
                                                     bnd_count, bnd_slot, bnd_w, processed);
    boundary_kernel<<<E_NUM, 256, 0, stream>>>(bnd_count, bnd_slot, bnd_w, rem,
                                               sel_count, sel_tok, sel_w, processed);
    init_out_kernel<<<(T_TOKENS * O_DIM / 4) / 256, 256, 0, stream>>>(xnb, processed, out);

    if (ws_size >= NEED_BIG) {
        // merged: one fc1 dispatch + one fc2 dispatch across all experts
        moe_gemm_kernel<1, 0, 1><<<dim3(CAP / 256, H_DIM / 256, E_NUM), 512, 0, stream>>>(
            xnb, W1t, b1, sel_tok, sel_w, sel_count, 0, D_DIM, H_DIM,
            0, (size_t)CAP * H_DIM, h, nullptr);
        moe_gemm_kernel<0, 2, 1><<<dim3(CAP / 256, O_DIM / 256, E_NUM), 512, 0, stream>>>(
            h, W2t, b2, sel_tok, sel_w, sel_count, 0, H_DIM, O_DIM,
            (size_t)CAP * H_DIM, 0, nullptr, out);
    } else {
        for (int e = 0; e < E_NUM; e++) {
            moe_gemm_kernel<1, 0, 0><<<dim3(CAP / 256, H_DIM / 256), 512, 0, stream>>>(
                xnb, W1t, b1, sel_tok, sel_w, sel_count, e, D_DIM, H_DIM,
                0, 0, h, nullptr);
            moe_gemm_kernel<0, 1, 0><<<dim3(CAP / 256, O_DIM / 256), 512, 0, stream>>>(
                h, W2t, b2, sel_tok, sel_w, sel_count, e, H_DIM, O_DIM,
                0, 0, nullptr, out);
        }
    }
}

// Round 7
// 910.834 us; speedup vs baseline: 7.9541x; 1.1027x over previous
//
#include <hip/hip_runtime.h>
#include <math.h>

typedef __attribute__((ext_vector_type(4))) float f32x4;
typedef __attribute__((ext_vector_type(8))) short short8;
typedef unsigned short u16;

#define T_TOKENS 65536
#define D_DIM    512
#define H_DIM    2048
#define O_DIM    512
#define E_NUM    8
#define CAP      8192

// ---- workspace layout (bytes) ----
static constexpr size_t OFF_COUNTS = 0;            // 8 ints
static constexpr size_t OFF_SELC   = 64;           // 8 ints
static constexpr size_t OFF_BNDC   = 128;          // 8 ints
static constexpr size_t OFF_PROC   = 192;          // T ints
static constexpr size_t OFF_HIST   = OFF_PROC + (size_t)T_TOKENS * 4;          // E*65536 uints (2MB)
static constexpr size_t CTRL_BYTES = OFF_HIST + (size_t)E_NUM * 65536 * 4;     // zeroed per launch
static constexpr size_t OFF_THR    = CTRL_BYTES;                               // 8 ints
static constexpr size_t OFF_REM    = OFF_THR + 64;                             // 8 ints
static constexpr size_t OFF_CANDW  = OFF_REM + 64;
static constexpr size_t OFF_CANDS  = OFF_CANDW + (size_t)E_NUM * T_TOKENS * 4; // +2MB
static constexpr size_t OFF_SELTOK = OFF_CANDS + (size_t)E_NUM * T_TOKENS * 4; // +2MB
static constexpr size_t OFF_SELW   = OFF_SELTOK + (size_t)E_NUM * CAP * 4;     // +256KB
static constexpr size_t OFF_LOG    = OFF_SELW + (size_t)E_NUM * CAP * 4;       // +256KB, 4MB region
// bnd arrays overlap logits region (logits dead before emit runs)
static constexpr size_t OFF_BNDS   = OFF_LOG;                                  // 1MB
static constexpr size_t OFF_BNDW   = OFF_LOG + (size_t)E_NUM * CAP * 4 * 4;    // 1MB
static constexpr size_t OFF_XNB    = OFF_LOG + (size_t)T_TOKENS * E_NUM * 8;   // +4MB
static constexpr size_t OFF_W1T    = OFF_XNB + (size_t)T_TOKENS * D_DIM * 2;   // +64MB
static constexpr size_t OFF_W2T    = OFF_W1T + (size_t)E_NUM * D_DIM * H_DIM * 2; // +16MB
static constexpr size_t OFF_H      = OFF_W2T + (size_t)E_NUM * H_DIM * O_DIM * 2; // +16MB
static constexpr size_t NEED_SMALL = OFF_H + (size_t)CAP * H_DIM * 2;             // ~139MB
static constexpr size_t NEED_BIG   = OFF_H + (size_t)E_NUM * CAP * H_DIM * 2;     // ~363MB

__device__ __forceinline__ u16 f2b(float f) {            // f32 -> bf16 RNE
    unsigned u = __float_as_uint(f);
    unsigned r = (u + 0x7FFFu + ((u >> 16) & 1u)) >> 16;
    return (u16)r;
}
__device__ __forceinline__ float b2f(u16 b) {
    return __uint_as_float(((unsigned)b) << 16);
}

// exact-accuracy GELU: erf via Abramowitz-Stegun 7.1.26 (|eps| <= 1.5e-7), branch-free.
// Replaces libm erff (multi-branch, ~60-100 VALU under divergence) with ~14 ops.
__device__ __forceinline__ float gelu_exact(float x) {
    float z = fabsf(x) * 0.70710678118654752440f;
    float tt = __builtin_amdgcn_rcpf(fmaf(0.3275911f, z, 1.0f));
    float poly = tt * fmaf(tt, fmaf(tt, fmaf(tt, fmaf(tt, 1.061405429f, -1.453152027f),
                       1.421413741f), -0.284496736f), 0.254829592f);
    float e = __expf(-z * z);
    float erf_abs = fmaf(-poly, e, 1.0f);
    float erfv = copysignf(erf_abs, x);
    return 0.5f * x * (1.0f + erfv);
}

#define AS1 __attribute__((address_space(1)))
#define AS3 __attribute__((address_space(3)))
__device__ __forceinline__ void gload_lds16(const void* g, void* l) {
    __builtin_amdgcn_global_load_lds((const AS1 void*)g, (AS3 void*)l, 16, 0, 0);
}

// ---------------- LayerNorm + fp64 logits (grid-stride: 64 tokens/block) ----------------
__global__ __launch_bounds__(256) void ln_kernel(
    const float* __restrict__ x, const float* __restrict__ gamma,
    const float* __restrict__ beta, const float* __restrict__ Wg,
    u16* __restrict__ xnb, double* __restrict__ logits)
{
    __shared__ float sWg[E_NUM * D_DIM];
    for (int i = threadIdx.x; i < E_NUM * D_DIM; i += 256) sWg[i] = Wg[i];
    __syncthreads();

    const int wave = threadIdx.x >> 6, lane = threadIdx.x & 63;

    for (int it = 0; it < 16; ++it) {
        const int t = blockIdx.x * 64 + it * 4 + wave;
        const float* xr = x + (size_t)t * D_DIM;

        float xv[8];
        #pragma unroll
        for (int i = 0; i < 8; i++) xv[i] = xr[i * 64 + lane];

        double s = 0.0;
        #pragma unroll
        for (int i = 0; i < 8; i++) s += (double)xv[i];
        #pragma unroll
        for (int o = 32; o > 0; o >>= 1) s += __shfl_xor(s, o);
        double mu = s / 512.0;

        double v = 0.0;
        #pragma unroll
        for (int i = 0; i < 8; i++) { double d = (double)xv[i] - mu; v += d * d; }
        #pragma unroll
        for (int o = 32; o > 0; o >>= 1) v += __shfl_xor(v, o);
        double rstd = 1.0 / sqrt(v / 512.0 + 1e-5);

        float xnf[8];
        #pragma unroll
        for (int i = 0; i < 8; i++) {
            int c = i * 64 + lane;
            double xd = ((double)xv[i] - mu) * rstd * (double)gamma[c] + (double)beta[c];
            xnf[i] = (float)xd;
            xnb[(size_t)t * D_DIM + c] = f2b(xnf[i]);
        }

        double p[E_NUM];
        #pragma unroll
        for (int e = 0; e < E_NUM; e++) p[e] = 0.0;
        #pragma unroll
        for (int i = 0; i < 8; i++) {
            int c = i * 64 + lane;
            double xd = (double)xnf[i];
            #pragma unroll
            for (int e = 0; e < E_NUM; e++) p[e] += xd * (double)sWg[e * D_DIM + c];
        }
        #pragma unroll
        for (int o = 32; o > 0; o >>= 1) {
            #pragma unroll
            for (int e = 0; e < E_NUM; e++) p[e] += __shfl_xor(p[e], o);
        }
        if (lane < 8) {
            double vv = p[0];
            #pragma unroll
            for (int e = 1; e < 8; e++) if (lane == e) vv = p[e];
            logits[(size_t)t * 8 + lane] = vv;
        }
    }
}

// ---------------- gate: softmax + top2 + normalize + 16b-prefix histogram ----------------
__global__ __launch_bounds__(256) void gate_kernel(
    const double* __restrict__ logits, const float* __restrict__ noise,
    const float* __restrict__ bg,
    int* __restrict__ counts, float* __restrict__ cand_w, int* __restrict__ cand_slot,
    unsigned int* __restrict__ hist)
{
    __shared__ int lcnt[E_NUM], lbase[E_NUM];
    if (threadIdx.x < E_NUM) lcnt[threadIdx.x] = 0;
    __syncthreads();
    const int t = blockIdx.x * 256 + threadIdx.x;

    double l[E_NUM], m = -1e300;
    #pragma unroll
    for (int e = 0; e < E_NUM; e++) {
        l[e] = logits[(size_t)t * 8 + e] + (double)bg[e] + 0.125 * (double)noise[(size_t)t * 8 + e];
        if (l[e] > m) m = l[e];
    }
    double sum = 0.0, g[E_NUM];
    #pragma unroll
    for (int e = 0; e < E_NUM; e++) { g[e] = exp(l[e] - m); sum += g[e]; }
    double inv = 1.0 / sum;
    #pragma unroll
    for (int e = 0; e < E_NUM; e++) g[e] *= inv;

    double v1 = -1.0; int i1 = 0;
    #pragma unroll
    for (int e = 0; e < E_NUM; e++) if (g[e] > v1) { v1 = g[e]; i1 = e; }
    double v2 = -1.0; int i2 = 0;
    #pragma unroll
    for (int e = 0; e < E_NUM; e++) if (e != i1 && g[e] > v2) { v2 = g[e]; i2 = e; }

    double denom = v1 + v2 + 1e-20;
    float w1 = (float)(v1 / denom);
    float w2 = (float)(v2 / denom);

    atomicAdd(&hist[(size_t)i1 * 65536 + ((~__float_as_uint(w1)) >> 16)], 1u);
    atomicAdd(&hist[(size_t)i2 * 65536 + ((~__float_as_uint(w2)) >> 16)], 1u);

    int p1 = atomicAdd(&lcnt[i1], 1);
    int p2 = atomicAdd(&lcnt[i2], 1);
    __syncthreads();
    if (threadIdx.x < E_NUM) lbase[threadIdx.x] = atomicAdd(&counts[threadIdx.x], lcnt[threadIdx.x]);
    __syncthreads();
    cand_w[(size_t)i1 * T_TOKENS + lbase[i1] + p1] = w1;
    cand_slot[(size_t)i1 * T_TOKENS + lbase[i1] + p1] = 2 * t;
    cand_w[(size_t)i2 * T_TOKENS + lbase[i2] + p2] = w2;
    cand_slot[(size_t)i2 * T_TOKENS + lbase[i2] + p2] = 2 * t + 1;
}

// ---------------- scan: find 16-bit threshold bin + residual need per expert ----------------
__global__ __launch_bounds__(1024) void scan_kernel(
    const unsigned int* __restrict__ hist, const int* __restrict__ counts,
    int* __restrict__ thr16, int* __restrict__ rem)
{
    const int e = blockIdx.x;
    const int n = counts[e];
    if (n <= CAP) {
        if (threadIdx.x == 0) { thr16[e] = 65536; rem[e] = 0; }
        return;
    }
    const unsigned int* h = hist + (size_t)e * 65536;
    __shared__ unsigned int part[1024];
    const int tid = threadIdx.x;
    unsigned int own = 0;
    const int base = tid * 64;
    #pragma unroll 8
    for (int i = 0; i < 64; i++) own += h[base + i];
    part[tid] = own;
    __syncthreads();
    for (int off = 1; off < 1024; off <<= 1) {
        unsigned int v = (tid >= off) ? part[tid - off] : 0u;
        __syncthreads();
        part[tid] += v;
        __syncthreads();
    }
    unsigned int incl = part[tid];
    unsigned int excl = incl - own;
    const unsigned int need = CAP;
    if (excl < need && incl >= need) {
        unsigned int cum = excl;
        for (int i = 0; i < 64; i++) {
            unsigned int hv = h[base + i];
            if (cum + hv >= need) { thr16[e] = base + i; rem[e] = (int)(need - cum); break; }
            cum += hv;
        }
    }
}

// ---------------- emit: select below-threshold candidates, collect boundary bin ----------------
__global__ __launch_bounds__(256) void emit_kernel(
    const int* __restrict__ counts, const float* __restrict__ cand_w,
    const int* __restrict__ cand_slot, const int* __restrict__ thr16,
    int* __restrict__ sel_count, int* __restrict__ sel_tok, float* __restrict__ sel_w,
    int* __restrict__ bnd_count, int* __restrict__ bnd_slot, float* __restrict__ bnd_w,
    int* __restrict__ processed)
{
    const int e = blockIdx.y;
    const int n = counts[e];
    const int thr = thr16[e];
    const float* cw = cand_w + (size_t)e * T_TOKENS;
    const int* cs = cand_slot + (size_t)e * T_TOKENS;
    for (int i = blockIdx.x * 256 + threadIdx.x; i < n; i += gridDim.x * 256) {
        float w = cw[i];
        int slot = cs[i];
        int p16 = (int)((~__float_as_uint(w)) >> 16);
        if (p16 < thr) {
            int pos = atomicAdd(&sel_count[e], 1);
            sel_tok[e * CAP + pos] = slot >> 1;
            sel_w[e * CAP + pos]  = w;
            processed[slot >> 1] = 1;
        } else if (p16 == thr) {
            int bpos = atomicAdd(&bnd_count[e], 1);
            bnd_slot[(size_t)e * CAP * 4 + bpos] = slot;
            bnd_w[(size_t)e * CAP * 4 + bpos]   = w;
        }
    }
}

// ---------------- boundary: exact rank among boundary-bin candidates ----------------
__global__ __launch_bounds__(256) void boundary_kernel(
    const int* __restrict__ bnd_count, const int* __restrict__ bnd_slot,
    const float* __restrict__ bnd_w, const int* __restrict__ rem,
    int* __restrict__ sel_count, int* __restrict__ sel_tok, float* __restrict__ sel_w,
    int* __restrict__ processed)
{
    const int e = blockIdx.x;
    const int r = rem[e];
    if (r == 0) return;
    const int nb = bnd_count[e];
    const int* bs = bnd_slot + (size_t)e * CAP * 4;
    const float* bw = bnd_w + (size_t)e * CAP * 4;
    for (int i = threadIdx.x; i < nb; i += 256) {
        unsigned long long ki = (((unsigned long long)(~__float_as_uint(bw[i]))) << 32) | (unsigned int)bs[i];
        int rank = 0;
        for (int j = 0; j < nb; j++) {
            unsigned long long kj = (((unsigned long long)(~__float_as_uint(bw[j]))) << 32) | (unsigned int)bs[j];
            rank += (kj < ki);
        }
        if (rank < r) {
            int pos = atomicAdd(&sel_count[e], 1);
            sel_tok[e * CAP + pos] = bs[i] >> 1;
            sel_w[e * CAP + pos]  = bw[i];
            processed[bs[i] >> 1] = 1;
        }
    }
}

// ---------------- W [E][K][N] f32 -> Wt [E][N][K] bf16 (tiled transpose) ----------------
__global__ __launch_bounds__(256) void convert_wt_kernel(
    const float* __restrict__ W, u16* __restrict__ Wt, int K, int N)
{
    __shared__ float tile[64][65];
    const int e = blockIdx.z;
    const int k0 = blockIdx.y * 64, n0 = blockIdx.x * 64;
    const float* We = W + (size_t)e * K * N;
    u16* Wte = Wt + (size_t)e * N * K;
    const int tx = threadIdx.x & 63, ty = threadIdx.x >> 6;
    #pragma unroll
    for (int r = 0; r < 64; r += 4)
        tile[ty + r][tx] = We[(size_t)(k0 + ty + r) * N + n0 + tx];
    __syncthreads();
    #pragma unroll
    for (int r = 0; r < 64; r += 4) {
        int nn = ty + r;
        Wte[(size_t)(n0 + nn) * K + k0 + tx] = f2b(tile[tx][nn]);
    }
}

// ---------------- out = processed ? 0 : xn ----------------
__global__ __launch_bounds__(256) void init_out_kernel(
    const u16* __restrict__ xnb, const int* __restrict__ processed, float* __restrict__ out)
{
    size_t i = (size_t)blockIdx.x * 256 + threadIdx.x;
    int t = (int)(i >> 7);
    float4 v; v.x = 0.f; v.y = 0.f; v.z = 0.f; v.w = 0.f;
    if (!processed[t]) {
        const u16* xp = xnb + (i << 2);
        v.x = b2f(xp[0]); v.y = b2f(xp[1]); v.z = b2f(xp[2]); v.w = b2f(xp[3]);
    }
    ((float4*)out)[i] = v;
}

// ---------------- bf16 MFMA GEMM: 256x256 tile, BK=64, 8 waves, dbuf, XOR-swizzle,
// counted-vmcnt pipeline (T4): issue tile t+1's loads at TOP of iter t, then vmcnt(8)
// (waits only tile t's 8 loads; t+1's stay in flight through compute). Writes to buf[nxt]
// are safe: all reads of that buffer finished before the previous end-of-iter barrier.
// EPI 0: h = bf16(gelu(acc+bias))   EPI 1: out[tok] += w*(acc+bias)   EPI 2: atomicAdd variant
template<int GATHER, int EPI, int MERGED>
__global__ __launch_bounds__(512) void moe_gemm_kernel(
    const u16* __restrict__ Abase, const u16* __restrict__ Btbase,
    const float* __restrict__ biasbase,
    const int* __restrict__ sel_tok, const float* __restrict__ sel_w,
    const int* __restrict__ sel_count, int e_arg, int K, int N,
    size_t a_estride, size_t h_estride,
    u16* __restrict__ h_out, float* __restrict__ out)
{
    __shared__ u16 sA[2][256 * 64];   // 32KB each buf
    __shared__ u16 sB[2][256 * 64];   // 32KB each buf

    const int e = MERGED ? blockIdx.z : e_arg;
    const int selc = sel_count[e];
    const int row0 = blockIdx.x * 256;
    if (row0 >= selc) return;
    const int n0 = blockIdx.y * 256;

    const u16* A = Abase + (size_t)e * a_estride;
    const u16* Bt = Btbase + (size_t)e * (size_t)N * K;
    const float* bias = biasbase + (size_t)e * N;
    const int* sel_tok_e = sel_tok + (size_t)e * CAP;
    const float* sel_w_e = sel_w + (size_t)e * CAP;

    const int t = threadIdx.x;            // 0..511
    const int lane = t & 63;
    const int w = t >> 6;                 // 0..7
    const int wm = (w >> 2) * 128;        // wave M base
    const int wn = (w & 3) * 64;          // wave N base
    const int lr = lane & 15;
    const int lg = lane >> 4;

    const int srow = t >> 3;                               // 0..63 : row within 64-row staging group
    const int sk   = (((t & 7) ^ (srow & 7)) * 8);         // pre-swizzled source k-offset (u16)

    const u16* asrc[4];
    #pragma unroll
    for (int i = 0; i < 4; i++) {
        int r = row0 + i * 64 + srow;
        int gr;
        if (GATHER) gr = (r < selc) ? sel_tok_e[r] : 0;
        else        gr = r;
        asrc[i] = A + (size_t)gr * K + sk;
    }
    const u16* bsrc[4];
    #pragma unroll
    for (int i = 0; i < 4; i++) {
        int nn = n0 + i * 64 + srow;
        bsrc[i] = Bt + (size_t)nn * K + sk;
    }

    f32x4 acc[8][4] = {};
    const int NT = K >> 6;

    // prologue: stage tile 0 into buffer 0 (no wait here; first iter's vmcnt covers it)
    #pragma unroll
    for (int i = 0; i < 4; i++) gload_lds16(asrc[i], &sA[0][i * 4096 + t * 8]);
    #pragma unroll
    for (int i = 0; i < 4; i++) gload_lds16(bsrc[i], &sB[0][i * 4096 + t * 8]);

    int cur = 0;
    for (int kt = 0; kt < NT; ++kt) {
        const int nxt = cur ^ 1;
        if (kt + 1 < NT) {           // issue next-tile loads first; they fly through compute
            const int ko = (kt + 1) << 6;
            #pragma unroll
            for (int i = 0; i < 4; i++) gload_lds16(asrc[i] + ko, &sA[nxt][i * 4096 + t * 8]);
            #pragma unroll
            for (int i = 0; i < 4; i++) gload_lds16(bsrc[i] + ko, &sB[nxt][i * 4096 + t * 8]);
            asm volatile("s_waitcnt vmcnt(8)" ::: "memory");   // tile kt's loads done; kt+1's in flight
        } else {
            asm volatile("s_waitcnt vmcnt(0)" ::: "memory");
        }
        __builtin_amdgcn_s_barrier();

        const u16* sAc = &sA[cur][0];
        const u16* sBc = &sB[cur][0];
        __builtin_amdgcn_s_setprio(1);
        #pragma unroll
        for (int kk = 0; kk < 64; kk += 32) {
            short8 af[8], bf[4];
            #pragma unroll
            for (int m = 0; m < 8; m++) {
                int ar = wm + m * 16 + lr;
                af[m] = *(const short8*)&sAc[ar * 64 + ((kk + lg * 8) ^ ((ar & 7) * 8))];
            }
            #pragma unroll
            for (int n = 0; n < 4; n++) {
                int br = wn + n * 16 + lr;
                bf[n] = *(const short8*)&sBc[br * 64 + ((kk + lg * 8) ^ ((br & 7) * 8))];
            }
            #pragma unroll
            for (int m = 0; m < 8; m++)
                #pragma unroll
                for (int n = 0; n < 4; n++)
                    acc[m][n] = __builtin_amdgcn_mfma_f32_16x16x32_bf16(af[m], bf[n], acc[m][n], 0, 0, 0);
        }
        __builtin_amdgcn_s_setprio(0);
        __builtin_amdgcn_s_barrier();
        cur = nxt;
    }

    if (EPI == 0) {
        u16* hO = h_out + (size_t)e * h_estride;
        #pragma unroll
        for (int m = 0; m < 8; m++) {
            int row = row0 + wm + m * 16 + lg * 4;
            #pragma unroll
            for (int n = 0; n < 4; n++) {
                int col = n0 + wn + n * 16 + lr;
                float bb = bias[col];
                #pragma unroll
                for (int r = 0; r < 4; r++) {
                    float vv = acc[m][n][r] + bb;
                    hO[(size_t)(row + r) * N + col] = f2b(gelu_exact(vv));
                }
            }
        }
    } else {
        #pragma unroll
        for (int m = 0; m < 8; m++) {
            int row = row0 + wm + m * 16 + lg * 4;
            #pragma unroll
            for (int r = 0; r < 4; r++) {
                int rr = row + r;
                if (rr < selc) {
                    int tok = sel_tok_e[rr];
                    float wgt = sel_w_e[rr];
                    float* orow = out + (size_t)tok * O_DIM;
                    #pragma unroll
                    for (int n = 0; n < 4; n++) {
                        int col = n0 + wn + n * 16 + lr;
                        float val = wgt * (acc[m][n][r] + bias[col]);
                        if (EPI == 2) atomicAdd(&orow[col], val);
                        else          orow[col] += val;
                    }
                }
            }
        }
    }
}

extern "C" void kernel_launch(void* const* d_in, const int* in_sizes, int n_in,
                              void* d_out, int out_size, void* d_ws, size_t ws_size,
                              hipStream_t stream) {
    const float* x     = (const float*)d_in[0];
    const float* noise = (const float*)d_in[1];
    const float* gamma = (const float*)d_in[2];
    const float* beta  = (const float*)d_in[3];
    const float* Wg    = (const float*)d_in[4];
    const float* bg    = (const float*)d_in[5];
    const float* W1    = (const float*)d_in[6];
    const float* b1    = (const float*)d_in[7];
    const float* W2    = (const float*)d_in[8];
    const float* b2    = (const float*)d_in[9];
    float* out = (float*)d_out;

    char* ws = (char*)d_ws;
    int*    counts    = (int*)(ws + OFF_COUNTS);
    int*    sel_count = (int*)(ws + OFF_SELC);
    int*    bnd_count = (int*)(ws + OFF_BNDC);
    int*    processed = (int*)(ws + OFF_PROC);
    unsigned int* hist = (unsigned int*)(ws + OFF_HIST);
    int*    thr16     = (int*)(ws + OFF_THR);
    int*    rem       = (int*)(ws + OFF_REM);
    float*  cand_w    = (float*)(ws + OFF_CANDW);
    int*    cand_slot = (int*)(ws + OFF_CANDS);
    int*    sel_tok   = (int*)(ws + OFF_SELTOK);
    float*  sel_w     = (float*)(ws + OFF_SELW);
    double* logits    = (double*)(ws + OFF_LOG);
    int*    bnd_slot  = (int*)(ws + OFF_BNDS);
    float*  bnd_w     = (float*)(ws + OFF_BNDW);
    u16*    xnb       = (u16*)(ws + OFF_XNB);
    u16*    W1t       = (u16*)(ws + OFF_W1T);
    u16*    W2t       = (u16*)(ws + OFF_W2T);
    u16*    h         = (u16*)(ws + OFF_H);

    hipMemsetAsync(ws, 0, CTRL_BYTES, stream);
    hipMemsetAsync((char*)d_out + (size_t)T_TOKENS * O_DIM * 4, 0, 4, stream);  // aux_loss = 0

    convert_wt_kernel<<<dim3(H_DIM / 64, D_DIM / 64, E_NUM), 256, 0, stream>>>(W1, W1t, D_DIM, H_DIM);
    convert_wt_kernel<<<dim3(O_DIM / 64, H_DIM / 64, E_NUM), 256, 0, stream>>>(W2, W2t, H_DIM, O_DIM);

    ln_kernel<<<T_TOKENS / 64, 256, 0, stream>>>(x, gamma, beta, Wg, xnb, logits);
    gate_kernel<<<T_TOKENS / 256, 256, 0, stream>>>(logits, noise, bg, counts, cand_w, cand_slot, hist);
    scan_kernel<<<E_NUM, 1024, 0, stream>>>(hist, counts, thr16, rem);
    emit_kernel<<<dim3(64, E_NUM), 256, 0, stream>>>(counts, cand_w, cand_slot, thr16,
                                                     sel_count, sel_tok, sel_w,
                                                     bnd_count, bnd_slot, bnd_w, processed);
    boundary_kernel<<<E_NUM, 256, 0, stream>>>(bnd_count, bnd_slot, bnd_w, rem,
                                               sel_count, sel_tok, sel_w, processed);
    init_out_kernel<<<(T_TOKENS * O_DIM / 4) / 256, 256, 0, stream>>>(xnb, processed, out);

    if (ws_size >= NEED_BIG) {
        // merged: one fc1 dispatch + one fc2 dispatch across all experts
        moe_gemm_kernel<1, 0, 1><<<dim3(CAP / 256, H_DIM / 256, E_NUM), 512, 0, stream>>>(
            xnb, W1t, b1, sel_tok, sel_w, sel_count, 0, D_DIM, H_DIM,
            0, (size_t)CAP * H_DIM, h, nullptr);
        moe_gemm_kernel<0, 2, 1><<<dim3(CAP / 256, O_DIM / 256, E_NUM), 512, 0, stream>>>(
            h, W2t, b2, sel_tok, sel_w, sel_count, 0, H_DIM, O_DIM,
            (size_t)CAP * H_DIM, 0, nullptr, out);
    } else {
        for (int e = 0; e < E_NUM; e++) {
            moe_gemm_kernel<1, 0, 0><<<dim3(CAP / 256, H_DIM / 256), 512, 0, stream>>>(
                xnb, W1t, b1, sel_tok, sel_w, sel_count, e, D_DIM, H_DIM,
                0, 0, h, nullptr);
            moe_gemm_kernel<0, 1, 0><<<dim3(CAP / 256, O_DIM / 256), 512, 0, stream>>>(
                h, W2t, b2, sel_tok, sel_w, sel_count, e, H_DIM, O_DIM,
                0, 0, nullptr, out);
        }
    }
}